// Round 5
// baseline (1429.426 us; speedup 1.0000x reference)
//
#include <hip/hip_runtime.h>

#define NPTS 16384
#define DIM 256
#define KAUG 288               // 256 dims + (hi,lo) norm dims + zero pad to 9*32
#define KNN 5
#define RPB 64                 // query rows per block
#define STRIPS 4
#define STRIP (NPTS / STRIPS)  // 4096
#define CTILE 128              // candidates per tile
#define NCB (STRIP / CTILE)    // 32
#define TOPS 8                 // per-strip shortlist depth
#define WINK 96                // k per staged A-window (3 mfma k-steps)
#define NWIN 3                 // KAUG / WINK

typedef _Float16 f16x8 __attribute__((ext_vector_type(8)));
typedef float    f32x4 __attribute__((ext_vector_type(4)));

// workspace byte offsets
#define WS_CNT   0
#define WS_NORMS 4096
#define WS_HI    69632                        // _Float16 [NPTS][KAUG]
#define WS_SL    (WS_HI + NPTS * KAUG * 2)    // int shortlist [NPTS][32]

// lexicographic (score, idx) ascending bubble insert, constant indices only
#define INSERT8(Ls, Li, sc, ix) do {                                          \
    if ((sc) < (Ls)[TOPS-1] || ((sc) == (Ls)[TOPS-1] && (ix) < (Li)[TOPS-1])) { \
        float _d = (sc); int _i = (ix);                                       \
        _Pragma("unroll")                                                     \
        for (int _e = 0; _e < TOPS; ++_e) {                                   \
            bool _lt = (_d < (Ls)[_e]) || (_d == (Ls)[_e] && _i < (Li)[_e]);  \
            float _td = (Ls)[_e]; int _ti = (Li)[_e];                         \
            if (_lt) { (Ls)[_e] = _d; (Li)[_e] = _i; _d = _td; _i = _ti; }    \
        }                                                                     \
    } } while (0)

// K0: fp16 copy of embeddings augmented with hi/lo norm dims; fp32 norms; cnt=0.
// hi[row] = [ fp16(emb_row) | h, l, 0 x30 ]  with h+l ~= ||row||^2 (err < 1e-4)
__global__ __launch_bounds__(256) void prep_kernel(const float* __restrict__ emb,
                                                   float* __restrict__ norms,
                                                   _Float16* __restrict__ hi,
                                                   int* __restrict__ cnt) {
    if (blockIdx.x == 0 && threadIdx.x == 0) *cnt = 0;
    int row = blockIdx.x * 4 + (threadIdx.x >> 6);
    int l   = threadIdx.x & 63;
    float4 v = *reinterpret_cast<const float4*>(emb + (size_t)row * DIM + l * 4);
    union { _Float16 h[4]; short4 s; } u;
    u.h[0] = (_Float16)v.x; u.h[1] = (_Float16)v.y;
    u.h[2] = (_Float16)v.z; u.h[3] = (_Float16)v.w;
    *reinterpret_cast<short4*>(hi + (size_t)row * KAUG + l * 4) = u.s;
    float s = v.x * v.x + v.y * v.y + v.z * v.z + v.w * v.w;
#pragma unroll
    for (int off = 32; off > 0; off >>= 1) s += __shfl_down(s, off, 64);
    float tot = __shfl(s, 0, 64);
    if (l == 0) norms[row] = tot;
    if (l < 8) {
        union { _Float16 h[4]; short4 s; } z;
        z.h[0] = (_Float16)0.f; z.h[1] = (_Float16)0.f;
        z.h[2] = (_Float16)0.f; z.h[3] = (_Float16)0.f;
        if (l == 0) {
            _Float16 hh = (_Float16)tot;
            _Float16 ll = (_Float16)(tot - (float)hh);
            z.h[0] = hh; z.h[1] = ll;
        }
        *reinterpret_cast<short4*>(hi + (size_t)row * KAUG + 256 + l * 4) = z.s;
    }
}

// K1: fp16 MFMA filter with norms folded into K. Block = 64 rows x 4096-cand strip.
// LDS k-major: At[12 kchunk][128 cand][8 f16], Bt[36 kchunk][64 row][8 f16] -> all
// fragment reads are lane-linear (conflict-free), staging addrs are shift/mask.
union SMem {
    struct {
        alignas(16) _Float16 Bt[36 * 64 * 8];    // 36864 B, full-K row panel (-2q | 1,1,0)
        alignas(16) _Float16 At[12 * 128 * 8];   // 24576 B, one 96-k window of cand tile
    } st;
    struct {
        alignas(16) float mgS[3][RPB][TOPS];
        alignas(16) int   mgI[3][RPB][TOPS];
    } mg;
};

__global__ __launch_bounds__(256, 2) void filter_kernel(const _Float16* __restrict__ hi,
                                                        int* __restrict__ shortlist) {
    __shared__ SMem sm;
    const int tid = threadIdx.x;
    const int w = tid >> 6;          // wave 0..3
    const int l = tid & 63;
    const int panel = blockIdx.x >> 2;
    const int strip = blockIdx.x & 3;   // XCD k serves strip k&3 -> L2 affinity
    const int qbase = panel * RPB;
    const int cand0 = strip * STRIP;

    // ---- stage B row panel once: transform [q] -> [-2q | 1,1,0...] ----
#pragma unroll
    for (int i = 0; i < 9; ++i) {
        int idx = tid + 256 * i;             // 0..2303
        int kc = idx >> 6;                   // kchunk 0..35
        int row = idx & 63;
        f16x8 v = 0;
        if (kc < 32) {
            v = *reinterpret_cast<const f16x8*>(hi + (size_t)(qbase + row) * KAUG + kc * 8);
#pragma unroll
            for (int e = 0; e < 8; ++e) v[e] = v[e] * (_Float16)-2.0f;
        } else if (kc == 32) {
            v[0] = (_Float16)1.0f; v[1] = (_Float16)1.0f;
        }
        *reinterpret_cast<f16x8*>((char*)sm.st.Bt + kc * 1024 + row * 16) = v;
    }

    float Ls[4][TOPS]; int Li_[4][TOPS];
#pragma unroll
    for (int rf = 0; rf < 4; ++rf)
#pragma unroll
        for (int e = 0; e < TOPS; ++e) { Ls[rf][e] = 3.0e38f; Li_[rf][e] = 0x7fffffff; }

    for (int cb = 0; cb < NCB; ++cb) {
        const int cbase = cand0 + cb * CTILE;
        f32x4 acc[2][4];
#pragma unroll
        for (int cf = 0; cf < 2; ++cf)
#pragma unroll
            for (int rf = 0; rf < 4; ++rf) acc[cf][rf] = (f32x4){0.f, 0.f, 0.f, 0.f};

        for (int win = 0; win < NWIN; ++win) {
            __syncthreads();   // prev window consumed (covers Bt writes on 1st pass)
            // stage A window: 24 x 1KB regions, 6 per wave; src addr = shift/mask
            for (int j = w; j < 24; j += 4) {
                int d  = j * 1024 + l * 16;
                int kc = d >> 11;              // kchunk-in-window 0..11
                int cd = (d >> 4) & 127;       // cand-in-tile
                const _Float16* g = hi + (size_t)(cbase + cd) * KAUG + win * WINK + kc * 8;
                __builtin_amdgcn_global_load_lds(
                    (const __attribute__((address_space(1))) void*)g,
                    (__attribute__((address_space(3))) void*)((char*)sm.st.At + j * 1024),
                    16, 0, 0);
            }
            __syncthreads();   // vmcnt(0) drain before reads

#pragma unroll
            for (int ks = 0; ks < 3; ++ks) {
                const int kcw = ks * 4 + (l >> 4);       // window kchunk 0..11
                const int kcg = win * 12 + kcw;          // global kchunk 0..35
                f16x8 af[2], bf[4];
#pragma unroll
                for (int cf = 0; cf < 2; ++cf)
                    af[cf] = *reinterpret_cast<const f16x8*>(
                        (char*)sm.st.At + kcw * 2048 + (w * 32 + cf * 16 + (l & 15)) * 16);
#pragma unroll
                for (int rf = 0; rf < 4; ++rf)
                    bf[rf] = *reinterpret_cast<const f16x8*>(
                        (char*)sm.st.Bt + kcg * 1024 + (rf * 16 + (l & 15)) * 16);
#pragma unroll
                for (int cf = 0; cf < 2; ++cf)
#pragma unroll
                    for (int rf = 0; rf < 4; ++rf)
                        acc[cf][rf] = __builtin_amdgcn_mfma_f32_16x16x32_f16(
                            af[cf], bf[rf], acc[cf][rf], 0, 0, 0);
            }
        }

        // epilogue: scores come straight from acc; cheap min-guard, rare insert
#pragma unroll
        for (int rf = 0; rf < 4; ++rf) {
            float m0 = fminf(fminf(acc[0][rf][0], acc[0][rf][1]),
                             fminf(acc[0][rf][2], acc[0][rf][3]));
            float m1 = fminf(fminf(acc[1][rf][0], acc[1][rf][1]),
                             fminf(acc[1][rf][2], acc[1][rf][3]));
            if (fminf(m0, m1) < Ls[rf][TOPS - 1]) {
#pragma unroll
                for (int cf = 0; cf < 2; ++cf)
#pragma unroll
                    for (int r = 0; r < 4; ++r) {
                        float sc = acc[cf][rf][r];
                        int ci = cbase + w * 32 + cf * 16 + (l >> 4) * 4 + r;
                        INSERT8(Ls[rf], Li_[rf], sc, ci);
                    }
            }
        }
    }

    // ---- in-wave butterfly across cand groups (snapshot semantics) ----
#pragma unroll
    for (int mask = 16; mask <= 32; mask <<= 1) {
#pragma unroll
        for (int rf = 0; rf < 4; ++rf) {
            float pd[TOPS]; int pi[TOPS];
#pragma unroll
            for (int e = 0; e < TOPS; ++e) {
                pd[e] = __shfl_xor(Ls[rf][e], mask, 64);
                pi[e] = __shfl_xor(Li_[rf][e], mask, 64);
            }
#pragma unroll
            for (int e = 0; e < TOPS; ++e) INSERT8(Ls[rf], Li_[rf], pd[e], pi[e]);
        }
    }

    // ---- cross-wave merge via LDS (waves 1-3 publish, wave 0 merges+writes) ----
    __syncthreads();             // stage buffers dead; reuse as merge scratch
    if (w > 0 && (l >> 4) == 0) {
#pragma unroll
        for (int rf = 0; rf < 4; ++rf) {
            int row = rf * 16 + l;
#pragma unroll
            for (int e = 0; e < TOPS; ++e) {
                sm.mg.mgS[w - 1][row][e] = Ls[rf][e];
                sm.mg.mgI[w - 1][row][e] = Li_[rf][e];
            }
        }
    }
    __syncthreads();
    if (w == 0 && (l >> 4) == 0) {
#pragma unroll
        for (int rf = 0; rf < 4; ++rf) {
            int row = rf * 16 + l;
            for (int t = 0; t < 3; ++t)
#pragma unroll
                for (int e = 0; e < TOPS; ++e)
                    INSERT8(Ls[rf], Li_[rf], sm.mg.mgS[t][row][e], sm.mg.mgI[t][row][e]);
            int* dst = shortlist + (size_t)(qbase + row) * 32 + strip * 8;
            int4 w0 = make_int4(Li_[rf][0], Li_[rf][1], Li_[rf][2], Li_[rf][3]);
            int4 w1 = make_int4(Li_[rf][4], Li_[rf][5], Li_[rf][6], Li_[rf][7]);
            *reinterpret_cast<int4*>(dst)     = w0;
            *reinterpret_cast<int4*>(dst + 4) = w1;
        }
    }
}

// K2: exact fp32 rescore of 32 shortlisted candidates per row; exact top-5 by
// (dist, idx) lexicographic; label match; atomic count. One wave per row.
__global__ __launch_bounds__(256) void rescore_kernel(const float* __restrict__ emb,
                                                      const int* __restrict__ labels,
                                                      const float* __restrict__ norms,
                                                      const int* __restrict__ shortlist,
                                                      int* __restrict__ cnt) {
    __shared__ float qrow[4][DIM];
    const int tid = threadIdx.x;
    const int w = tid >> 6;
    const int l = tid & 63;
    const int q = blockIdx.x * 4 + w;

    float4 qv = *reinterpret_cast<const float4*>(emb + (size_t)q * DIM + l * 4);
    *reinterpret_cast<float4*>(&qrow[w][l * 4]) = qv;
    __syncthreads();

    float dloc = 3.0e38f; int iloc = 0x7fffffff;
    if (l < 32) {
        int ci = shortlist[(size_t)q * 32 + l];
        if (ci != q) {
            const float* crow = emb + (size_t)ci * DIM;
            float p0 = 0.f, p1 = 0.f, p2 = 0.f, p3 = 0.f;
#pragma unroll 8
            for (int kk = 0; kk < 64; ++kk) {
                float4 c4 = *reinterpret_cast<const float4*>(crow + kk * 4);
                float4 q4 = *reinterpret_cast<const float4*>(&qrow[w][kk * 4]);
                p0 = fmaf(c4.x, q4.x, p0);
                p1 = fmaf(c4.y, q4.y, p1);
                p2 = fmaf(c4.z, q4.z, p2);
                p3 = fmaf(c4.w, q4.w, p3);
            }
            float dot = (p0 + p1) + (p2 + p3);
            dloc = fmaf(-2.0f, dot, norms[q] + norms[ci]);
            iloc = ci;
        }
    }

    const int lq = labels[q];
    bool match = false;
#pragma unroll
    for (int r = 0; r < KNN; ++r) {
        float md = dloc; int mi = iloc;
#pragma unroll
        for (int mask = 1; mask <= 32; mask <<= 1) {
            float pd = __shfl_xor(md, mask, 64);
            int   pi = __shfl_xor(mi, mask, 64);
            if (pd < md || (pd == md && pi < mi)) { md = pd; mi = pi; }
        }
        if (iloc == mi) dloc = 3.0e38f;   // owner retires its candidate
        match = match || (labels[mi] == lq);
    }
    if (l == 0) atomicAdd(cnt, match ? 1 : 0);
}

// K3: scalar output = count / N (power-of-two divide, exact)
__global__ void finalize_kernel(const int* __restrict__ cnt, float* __restrict__ out) {
    if (threadIdx.x == 0) out[0] = (float)(*cnt) * (1.0f / (float)NPTS);
}

extern "C" void kernel_launch(void* const* d_in, const int* in_sizes, int n_in,
                              void* d_out, int out_size, void* d_ws, size_t ws_size,
                              hipStream_t stream) {
    (void)in_sizes; (void)n_in; (void)out_size; (void)ws_size;
    const float* emb    = (const float*)d_in[0];
    const int*   labels = (const int*)d_in[1];
    float*       out    = (float*)d_out;

    char* ws = (char*)d_ws;
    int*      cnt       = (int*)(ws + WS_CNT);
    float*    norms     = (float*)(ws + WS_NORMS);
    _Float16* hi        = (_Float16*)(ws + WS_HI);
    int*      shortlist = (int*)(ws + WS_SL);

    prep_kernel<<<NPTS / 4, 256, 0, stream>>>(emb, norms, hi, cnt);
    filter_kernel<<<(NPTS / RPB) * STRIPS, 256, 0, stream>>>(hi, shortlist);
    rescore_kernel<<<NPTS / 4, 256, 0, stream>>>(emb, labels, norms, shortlist, cnt);
    finalize_kernel<<<1, 64, 0, stream>>>(cnt, out);
}

// Round 6
// 1331.893 us; speedup vs baseline: 1.0732x; 1.0732x over previous
//
#include <hip/hip_runtime.h>

#define NPTS 16384
#define DIM 256
#define KAUG 288               // 256 dims + (h,l) norm chunk + zero pad = 36 kchunks
#define NKC 36
#define KNN 5
#define RPB 64                 // rows per block (4 waves x 16)
#define CTILE 128              // candidates per tile
#define STRIPS 8
#define STRIP (NPTS / STRIPS)  // 2048
#define NCB (STRIP / CTILE)    // 16
#define TOPS 7                 // per-strip shortlist depth (self + 5 + 1 spare)

typedef _Float16 f16x8 __attribute__((ext_vector_type(8)));
typedef float    f32x4 __attribute__((ext_vector_type(4)));
typedef unsigned short ushort_t;

// workspace byte offsets
#define WS_CNT   0
#define WS_NORMS 4096                          // float [NPTS]
#define WS_HIA   (WS_NORMS + NPTS * 4)         // _Float16 [NKC][NPTS][8] k-major
#define WS_SL    (WS_HIA + NPTS * KAUG * 2)    // ushort [NPTS][STRIPS*TOPS]

// unsorted top-7 keeper: list (Ls,Li) + cached lex-max (ms,mi). Insert x iff
// x <lex (ms,mi): replace the max slot, recompute max. All indices static.
#define INSERT_RM(sc, ci) do {                                                \
    if ((sc) < ms || ((sc) == ms && (ci) < mi)) {                             \
        bool _done = false;                                                   \
        _Pragma("unroll")                                                     \
        for (int _e = 0; _e < TOPS; ++_e) {                                   \
            bool _isM = (!_done) && (Ls[_e] == ms) && (Li[_e] == mi);         \
            if (_isM) { Ls[_e] = (sc); Li[_e] = (ci); _done = true; }         \
        }                                                                     \
        ms = Ls[0]; mi = Li[0];                                               \
        _Pragma("unroll")                                                     \
        for (int _e = 1; _e < TOPS; ++_e) {                                   \
            bool _gt = (Ls[_e] > ms) || (Ls[_e] == ms && Li[_e] > mi);        \
            if (_gt) { ms = Ls[_e]; mi = Li[_e]; }                            \
        }                                                                     \
    } } while (0)

// K0: build k-major augmented fp16 candidate buffer hiA_t[kc][cand][8]:
// chunks 0..31 = -2*fp16(c), chunk 32 = [h,l,0...] (h+l ~= ||c||^2), 33..35 = 0.
// Also fp32 norms and counter zero. One wave per row.
__global__ __launch_bounds__(256) void prep_kernel(const float* __restrict__ emb,
                                                   float* __restrict__ norms,
                                                   _Float16* __restrict__ hiA,
                                                   int* __restrict__ cnt) {
    if (blockIdx.x == 0 && threadIdx.x == 0) *cnt = 0;
    const int row = blockIdx.x * 4 + (threadIdx.x >> 6);
    const int l   = threadIdx.x & 63;
    float4 v = *reinterpret_cast<const float4*>(emb + (size_t)row * DIM + l * 4);
    union { _Float16 h[4]; short4 s; } u;
    u.h[0] = (_Float16)v.x * (_Float16)-2.0f;
    u.h[1] = (_Float16)v.y * (_Float16)-2.0f;
    u.h[2] = (_Float16)v.z * (_Float16)-2.0f;
    u.h[3] = (_Float16)v.w * (_Float16)-2.0f;
    *reinterpret_cast<short4*>(hiA + ((size_t)(l >> 1) * NPTS + row) * 8 + (l & 1) * 4) = u.s;

    float s = v.x * v.x + v.y * v.y + v.z * v.z + v.w * v.w;
#pragma unroll
    for (int off = 32; off > 0; off >>= 1) s += __shfl_down(s, off, 64);
    float tot = __shfl(s, 0, 64);
    if (l == 0) norms[row] = tot;
    if (l < 4) {   // chunks 32..35: lane0 = [h,l,0...], lanes 1-3 = zeros
        union { _Float16 h[4]; short4 s; } z0, z1;
        z0.h[0] = (_Float16)0.f; z0.h[1] = (_Float16)0.f;
        z0.h[2] = (_Float16)0.f; z0.h[3] = (_Float16)0.f;
        z1 = z0;
        if (l == 0) {
            _Float16 hh = (_Float16)tot;
            _Float16 ll = (_Float16)(tot - (float)hh);
            z0.h[0] = hh; z0.h[1] = ll;
        }
        _Float16* dst = hiA + ((size_t)(32 + l) * NPTS + row) * 8;
        *reinterpret_cast<short4*>(dst)     = z0.s;
        *reinterpret_cast<short4*>(dst + 4) = z1.s;
    }
}

// K1: MFMA filter. Block = 64 rows x 2048-cand strip; 4 waves x (16 rows x 128 cands).
// B (rows): full-K in LDS, derived from hiA * -0.5 (chunk32 -> [1,1,0..]).
// A (cands): per-64k-step double-buffered via coalesced global_load_lds.
// score = ||c||^2 - 2 q.c comes straight out of the MFMA (norms folded).
__global__ __launch_bounds__(256, 2) void filter_kernel(const _Float16* __restrict__ hiA,
                                                        ushort_t* __restrict__ shortlist) {
    __shared__ _Float16 Bt[NKC * 64 * 8];      // 36864 B [kc][row][8]
    __shared__ _Float16 At[2 * 8 * CTILE * 8]; // 32768 B [buf][kc_in_win][cand][8]
    const int tid = threadIdx.x;
    const int w = tid >> 6;
    const int l = tid & 63;
    const int panel = blockIdx.x >> 3;
    const int strip = blockIdx.x & 7;          // strip == native XCD slot -> L2 affinity
    const int qbase = panel * RPB;
    const int cand0 = strip * STRIP;

    // ---- stage B row panel once (register path, coalesced reads) ----
#pragma unroll
    for (int j = 0; j < 9; ++j) {
        int idx = tid + 256 * j;               // 0..2303 = 36 kc * 64 rows
        int kc = idx >> 6, row = idx & 63;
        f16x8 v;
        if (kc < 32) {
            v = *reinterpret_cast<const f16x8*>(hiA + ((size_t)kc * NPTS + qbase + row) * 8);
#pragma unroll
            for (int e = 0; e < 8; ++e) v[e] = v[e] * (_Float16)-0.5f;  // -0.5 * (-2q) = q, exact
        } else {
#pragma unroll
            for (int e = 0; e < 8; ++e) v[e] = (_Float16)0.f;
            if (kc == 32) { v[0] = (_Float16)1.0f; v[1] = (_Float16)1.0f; }
        }
        *reinterpret_cast<f16x8*>(Bt + idx * 8) = v;
    }

    // per-lane unsorted top-7 for owner row (qbase + w*16 + (l&15))
    float Ls[TOPS]; int Li[TOPS];
#pragma unroll
    for (int e = 0; e < TOPS; ++e) { Ls[e] = 3.0e38f; Li[e] = 0x7fffffff; }
    float ms = 3.0e38f; int mi = 0x7fffffff;

    // ---- prologue: stage A (cb=0, s=0) into buf 0 ----
    {
#pragma unroll
        for (int i = 0; i < 4; ++i) {
            int d = i * 4096 + tid * 16;
            int kc = d >> 11, cd = (d >> 4) & 127;
            const _Float16* g = hiA + ((size_t)kc * NPTS + cand0 + cd) * 8;
            __builtin_amdgcn_global_load_lds(
                (const __attribute__((address_space(1))) void*)g,
                (__attribute__((address_space(3))) void*)((char*)At + d), 16, 0, 0);
        }
    }
    __syncthreads();   // drains Bt ds_writes + At vmcnt

    int buf = 0;
    for (int cb = 0; cb < NCB; ++cb) {
        const int cbase = cand0 + cb * CTILE;
        f32x4 acc[8];
#pragma unroll
        for (int cf = 0; cf < 8; ++cf) acc[cf] = (f32x4){0.f, 0.f, 0.f, 0.f};

        for (int s = 0; s < 5; ++s) {
            // issue next-step staging into the other buffer (hidden under compute)
            int sn = s + 1, cbn = cb;
            if (sn == 5) { sn = 0; cbn = cb + 1; }
            if (cbn < NCB) {
                const int cbase_n = cand0 + cbn * CTILE;
                const int nIss = (sn == 4) ? 2 : 4;     // last K-step = 4 kchunks only
                for (int i = 0; i < nIss; ++i) {
                    int d = i * 4096 + tid * 16;
                    int kc = d >> 11, cd = (d >> 4) & 127;
                    const _Float16* g = hiA + ((size_t)(sn * 8 + kc) * NPTS + cbase_n + cd) * 8;
                    __builtin_amdgcn_global_load_lds(
                        (const __attribute__((address_space(1))) void*)g,
                        (__attribute__((address_space(3))) void*)((char*)At + (buf ^ 1) * 16384 + d),
                        16, 0, 0);
                }
            }

            // compute: nks MFMA k-steps from At[buf] / Bt
            const _Float16* Ab = At + buf * 8192;
            const int nks = (s == 4) ? 1 : 2;
            for (int ks = 0; ks < nks; ++ks) {
                f16x8 bf = *reinterpret_cast<const f16x8*>(
                    Bt + (((s * 8 + ks * 4 + (l >> 4)) * 64) + w * 16 + (l & 15)) * 8);
#pragma unroll
                for (int cf = 0; cf < 8; ++cf) {
                    f16x8 af = *reinterpret_cast<const f16x8*>(
                        Ab + ((ks * 4 + (l >> 4)) * CTILE + cf * 16 + (l & 15)) * 8);
                    acc[cf] = __builtin_amdgcn_mfma_f32_16x16x32_f16(af, bf, acc[cf], 0, 0, 0);
                }
            }

            if (s == 4) {
                // epilogue: 32 scores for the owner row; vec-guard + rare insert
#pragma unroll
                for (int cf = 0; cf < 8; ++cf) {
                    float s0 = acc[cf][0], s1 = acc[cf][1];
                    float s2 = acc[cf][2], s3 = acc[cf][3];
                    float vmin = fminf(fminf(s0, s1), fminf(s2, s3));
                    if (vmin <= ms) {
                        int c0 = cbase + cf * 16 + ((l >> 4) << 2);
                        INSERT_RM(s0, c0 + 0);
                        INSERT_RM(s1, c0 + 1);
                        INSERT_RM(s2, c0 + 2);
                        INSERT_RM(s3, c0 + 3);
                    }
                }
            }
            __syncthreads();   // next buffer ready (compiler drains vmcnt before barrier)
            buf ^= 1;
        }
    }

    // ---- merge the 4 cand-partitions per row (snapshot butterfly over l>>4) ----
#pragma unroll
    for (int mask = 16; mask <= 32; mask <<= 1) {
        float pd[TOPS]; int pi[TOPS];
#pragma unroll
        for (int e = 0; e < TOPS; ++e) {
            pd[e] = __shfl_xor(Ls[e], mask, 64);
            pi[e] = __shfl_xor(Li[e], mask, 64);
        }
#pragma unroll
        for (int e = 0; e < TOPS; ++e) INSERT_RM(pd[e], pi[e]);
    }

    if ((l >> 4) == 0) {   // lanes 0..15 hold final per-strip top-7 for their row
        int row = qbase + w * 16 + l;
        ushort_t* dst = shortlist + (size_t)row * (STRIPS * TOPS) + strip * TOPS;
#pragma unroll
        for (int e = 0; e < TOPS; ++e) dst[e] = (ushort_t)Li[e];
    }
}

// K2: exact fp32 rescore. One block per query row; 4 threads per candidate;
// exact (dist, idx) lexicographic top-5; label match; atomic count.
__global__ __launch_bounds__(256) void rescore_kernel(const float* __restrict__ emb,
                                                      const int* __restrict__ labels,
                                                      const float* __restrict__ norms,
                                                      const ushort_t* __restrict__ shortlist,
                                                      int* __restrict__ cnt) {
    __shared__ float qrow[DIM];
    __shared__ float ds[64];
    __shared__ int   di[64];
    const int q = blockIdx.x;
    const int tid = threadIdx.x;
    if (tid < 64)
        *reinterpret_cast<float4*>(qrow + tid * 4) =
            *reinterpret_cast<const float4*>(emb + (size_t)q * DIM + tid * 4);
    __syncthreads();

    const int cslot = tid >> 2, part = tid & 3;
    float dv = 3.0e38f; int civ = 0x7fffffff;
    if (cslot < STRIPS * TOPS) {
        int c = shortlist[(size_t)q * (STRIPS * TOPS) + cslot];
        if (c != q) {   // uniform within the 4-lane group -> shuffles are safe
            const float* crow = emb + (size_t)c * DIM + part * 64;
            const float* qr = qrow + part * 64;
            float p0 = 0.f, p1 = 0.f, p2 = 0.f, p3 = 0.f;
#pragma unroll
            for (int kk = 0; kk < 16; ++kk) {
                float4 cv = *reinterpret_cast<const float4*>(crow + kk * 4);
                float4 qv = *reinterpret_cast<const float4*>(qr + kk * 4);
                p0 = fmaf(cv.x, qv.x, p0); p1 = fmaf(cv.y, qv.y, p1);
                p2 = fmaf(cv.z, qv.z, p2); p3 = fmaf(cv.w, qv.w, p3);
            }
            float p = (p0 + p1) + (p2 + p3);
            p += __shfl_xor(p, 1, 64);
            p += __shfl_xor(p, 2, 64);
            if (part == 0) { dv = fmaf(-2.0f, p, norms[q] + norms[c]); civ = c; }
        }
    }
    if (part == 0) { ds[cslot] = dv; di[cslot] = civ; }
    __syncthreads();

    if (tid < 64) {
        float dl = ds[tid]; int il = di[tid];
        const int lq = labels[q];
        bool match = false;
#pragma unroll
        for (int r = 0; r < KNN; ++r) {
            float md = dl; int mx = il;
#pragma unroll
            for (int mask = 1; mask <= 32; mask <<= 1) {
                float pd = __shfl_xor(md, mask, 64);
                int   pi = __shfl_xor(mx, mask, 64);
                if (pd < md || (pd == md && pi < mx)) { md = pd; mx = pi; }
            }
            if (il == mx) dl = 3.0e38f;   // owner retires its candidate
            match = match || (labels[mx] == lq);
        }
        if (tid == 0) atomicAdd(cnt, match ? 1 : 0);
    }
}

// K3: scalar output = count / N (power-of-two divide, exact)
__global__ void finalize_kernel(const int* __restrict__ cnt, float* __restrict__ out) {
    if (threadIdx.x == 0) out[0] = (float)(*cnt) * (1.0f / (float)NPTS);
}

extern "C" void kernel_launch(void* const* d_in, const int* in_sizes, int n_in,
                              void* d_out, int out_size, void* d_ws, size_t ws_size,
                              hipStream_t stream) {
    (void)in_sizes; (void)n_in; (void)out_size; (void)ws_size;
    const float* emb    = (const float*)d_in[0];
    const int*   labels = (const int*)d_in[1];
    float*       out    = (float*)d_out;

    char* ws = (char*)d_ws;
    int*       cnt       = (int*)(ws + WS_CNT);
    float*     norms     = (float*)(ws + WS_NORMS);
    _Float16*  hiA       = (_Float16*)(ws + WS_HIA);
    ushort_t*  shortlist = (ushort_t*)(ws + WS_SL);

    prep_kernel<<<NPTS / 4, 256, 0, stream>>>(emb, norms, hiA, cnt);
    filter_kernel<<<(NPTS / RPB) * STRIPS, 256, 0, stream>>>(hiA, shortlist);
    rescore_kernel<<<NPTS, 256, 0, stream>>>(emb, labels, norms, shortlist, cnt);
    finalize_kernel<<<1, 64, 0, stream>>>(cnt, out);
}

// Round 7
// 1038.388 us; speedup vs baseline: 1.3766x; 1.2827x over previous
//
#include <hip/hip_runtime.h>

#define NPTS 16384
#define DIM 256
#define NKC 36                 // augmented kchunks (8 halfs each): 32 data + (h,l) + pad
#define KNN 5
#define RPB 128                // rows per block = 4 waves x 32
#define CTILE 64               // candidates per tile
#define STRIPS 4
#define STRIP (NPTS / STRIPS)  // 4096
#define NCB (STRIP / CTILE)    // 64
#define TOPS 7                 // per-strip shortlist depth (self + 5 + 1 spare)
#define SLW (STRIPS * TOPS)    // 28 shortlist slots per row

typedef _Float16 f16x8 __attribute__((ext_vector_type(8)));
typedef float    f32x4 __attribute__((ext_vector_type(4)));
typedef unsigned short ushort_t;

// workspace byte offsets
#define WS_CNT   0
#define WS_NORMS 4096                          // float [NPTS]
#define WS_HIA   (WS_NORMS + NPTS * 4)         // _Float16 [NKC][NPTS][8] k-major
#define WS_SL    (WS_HIA + NPTS * NKC * 16)    // ushort [NPTS][SLW]

// unsorted top-7 keeper: list (Ls,Li) + cached lex-max (ms,mi). Insert x iff
// x <lex (ms,mi): replace the max slot, recompute max. All indices static.
#define INSERT_RM(Ls, Li, ms, mi, sc, ci) do {                                \
    if ((sc) < ms || ((sc) == ms && (ci) < mi)) {                             \
        bool _done = false;                                                   \
        _Pragma("unroll")                                                     \
        for (int _e = 0; _e < TOPS; ++_e) {                                   \
            bool _isM = (!_done) && (Ls[_e] == ms) && (Li[_e] == mi);         \
            if (_isM) { Ls[_e] = (sc); Li[_e] = (ci); _done = true; }         \
        }                                                                     \
        ms = Ls[0]; mi = Li[0];                                               \
        _Pragma("unroll")                                                     \
        for (int _e = 1; _e < TOPS; ++_e) {                                   \
            bool _gt = (Ls[_e] > ms) || (Ls[_e] == ms && Li[_e] > mi);        \
            if (_gt) { ms = Ls[_e]; mi = Li[_e]; }                            \
        }                                                                     \
    } } while (0)

// K0: build k-major augmented fp16 candidate buffer hiA[kc][cand][8]:
// chunks 0..31 = -2*fp16(c), chunk 32 = [h,l,0...] (h+l ~= ||c||^2), 33..35 = 0.
__global__ __launch_bounds__(256) void prep_kernel(const float* __restrict__ emb,
                                                   float* __restrict__ norms,
                                                   _Float16* __restrict__ hiA,
                                                   int* __restrict__ cnt) {
    if (blockIdx.x == 0 && threadIdx.x == 0) *cnt = 0;
    const int row = blockIdx.x * 4 + (threadIdx.x >> 6);
    const int l   = threadIdx.x & 63;
    float4 v = *reinterpret_cast<const float4*>(emb + (size_t)row * DIM + l * 4);
    union { _Float16 h[4]; short4 s; } u;
    u.h[0] = (_Float16)v.x * (_Float16)-2.0f;
    u.h[1] = (_Float16)v.y * (_Float16)-2.0f;
    u.h[2] = (_Float16)v.z * (_Float16)-2.0f;
    u.h[3] = (_Float16)v.w * (_Float16)-2.0f;
    *reinterpret_cast<short4*>(hiA + ((size_t)(l >> 1) * NPTS + row) * 8 + (l & 1) * 4) = u.s;

    float s = v.x * v.x + v.y * v.y + v.z * v.z + v.w * v.w;
#pragma unroll
    for (int off = 32; off > 0; off >>= 1) s += __shfl_down(s, off, 64);
    float tot = __shfl(s, 0, 64);
    if (l == 0) norms[row] = tot;
    if (l < 4) {   // chunks 32..35
        union { _Float16 h[4]; short4 s; } z0, z1;
        z0.h[0] = (_Float16)0.f; z0.h[1] = (_Float16)0.f;
        z0.h[2] = (_Float16)0.f; z0.h[3] = (_Float16)0.f;
        z1 = z0;
        if (l == 0) {
            _Float16 hh = (_Float16)tot;
            _Float16 ll = (_Float16)(tot - (float)hh);
            z0.h[0] = hh; z0.h[1] = ll;
        }
        _Float16* dst = hiA + ((size_t)(32 + l) * NPTS + row) * 8;
        *reinterpret_cast<short4*>(dst)     = z0.s;
        *reinterpret_cast<short4*>(dst + 4) = z1.s;
    }
}

// K1: MFMA filter. Block = 128 rows x 4096-cand strip; wave = 32 rows.
// B (rows): full-K in REGISTERS (16x f16x8/lane), derived from hiA * -0.5.
// A (cands): full-K 64-cand tiles in LDS, double-buffered, ONE barrier/tile.
// score = ||c||^2 - 2 q.c directly out of the MFMA (norms folded into K).
__global__ __launch_bounds__(256, 2) void filter_kernel(const _Float16* __restrict__ hiA,
                                                        ushort_t* __restrict__ shortlist) {
    __shared__ _Float16 At[2 * NKC * CTILE * 8];   // 73728 B
    const int tid  = threadIdx.x;
    const int w    = tid >> 6;
    const int l    = tid & 63;
    const int lq16 = l & 15;       // query-row-in-16 == D col
    const int lk4  = l >> 4;       // k-quarter / cand sub-group
    const int panel = blockIdx.x >> 2;
    const int strip = blockIdx.x & 3;     // XCD x serves strip x&3 -> L2-resident slice
    const int qbase = panel * RPB;
    const int cand0 = strip * STRIP;

    // ---- B fragments in registers: 2 rf x 8 t; kc = t*4+lk4; coalesced loads ----
    f16x8 breg0[8], breg1[8];
#pragma unroll
    for (int t = 0; t < 8; ++t) {
        const size_t r0 = (size_t)qbase + w * 32 + lq16;
        f16x8 v0 = *reinterpret_cast<const f16x8*>(hiA + ((size_t)(t * 4 + lk4) * NPTS + r0) * 8);
        f16x8 v1 = *reinterpret_cast<const f16x8*>(hiA + ((size_t)(t * 4 + lk4) * NPTS + r0 + 16) * 8);
#pragma unroll
        for (int e = 0; e < 8; ++e) {          // -0.5 * (-2q) = q, exact in fp16
            v0[e] = v0[e] * (_Float16)-0.5f;
            v1[e] = v1[e] * (_Float16)-0.5f;
        }
        breg0[t] = v0; breg1[t] = v1;
    }
    f16x8 breg8 = 0;                           // augmented chunk: [1,1,0..] on quarter 0
    if (lk4 == 0) { breg8[0] = (_Float16)1.0f; breg8[1] = (_Float16)1.0f; }

    float Ls0[TOPS], Ls1[TOPS]; int Li0[TOPS], Li1[TOPS];
#pragma unroll
    for (int e = 0; e < TOPS; ++e) {
        Ls0[e] = 3.0e38f; Li0[e] = 0x7fffffff;
        Ls1[e] = 3.0e38f; Li1[e] = 0x7fffffff;
    }
    float ms0 = 3.0e38f, ms1 = 3.0e38f; int mi0 = 0x7fffffff, mi1 = 0x7fffffff;

    // ---- prologue: stage tile 0 (full K) into buf 0; dest = wave-uniform + lane*16 ----
#pragma unroll
    for (int i = 0; i < 9; ++i) {
        int d = i * 4096 + tid * 16;
        int kc = d >> 10, cd = (d >> 4) & 63;
        const _Float16* g = hiA + ((size_t)kc * NPTS + cand0 + cd) * 8;
        __builtin_amdgcn_global_load_lds(
            (const __attribute__((address_space(1))) void*)g,
            (__attribute__((address_space(3))) void*)((char*)At + d), 16, 0, 0);
    }
    __syncthreads();

    int buf = 0;
    for (int cb = 0; cb < NCB; ++cb) {
        // prefetch next tile into the other buffer; lands during this tile's compute
        if (cb + 1 < NCB) {
            const int cbn = cand0 + (cb + 1) * CTILE;
#pragma unroll
            for (int i = 0; i < 9; ++i) {
                int d = i * 4096 + tid * 16;
                int kc = d >> 10, cd = (d >> 4) & 63;
                const _Float16* g = hiA + ((size_t)kc * NPTS + cbn + cd) * 8;
                __builtin_amdgcn_global_load_lds(
                    (const __attribute__((address_space(1))) void*)g,
                    (__attribute__((address_space(3))) void*)((char*)At + (buf ^ 1) * 36864 + d),
                    16, 0, 0);
            }
        }

        // compute: 9 k-steps x 4 cf x 2 rf = 72 MFMAs, zero barriers inside
        const char* Ab = (const char*)At + buf * 36864;
        f32x4 acc0[4], acc1[4];
#pragma unroll
        for (int cf = 0; cf < 4; ++cf) {
            acc0[cf] = (f32x4){0.f, 0.f, 0.f, 0.f};
            acc1[cf] = (f32x4){0.f, 0.f, 0.f, 0.f};
        }
#pragma unroll
        for (int t = 0; t < 9; ++t) {
            f16x8 bf0 = (t < 8) ? breg0[t] : breg8;
            f16x8 bf1 = (t < 8) ? breg1[t] : breg8;
#pragma unroll
            for (int cf = 0; cf < 4; ++cf) {
                f16x8 af = *reinterpret_cast<const f16x8*>(
                    Ab + (size_t)((t * 4 + lk4) * 64 + cf * 16 + lq16) * 16);
                acc0[cf] = __builtin_amdgcn_mfma_f32_16x16x32_f16(af, bf0, acc0[cf], 0, 0, 0);
                acc1[cf] = __builtin_amdgcn_mfma_f32_16x16x32_f16(af, bf1, acc1[cf], 0, 0, 0);
            }
        }

        // epilogue: 16 scores per rf; vec-min guard, rare exact insert
        const int cbase = cand0 + cb * CTILE;
#pragma unroll
        for (int cf = 0; cf < 4; ++cf) {
            const int c0 = cbase + cf * 16 + (lk4 << 2);
            {
                float s0 = acc0[cf][0], s1 = acc0[cf][1], s2 = acc0[cf][2], s3 = acc0[cf][3];
                if (fminf(fminf(s0, s1), fminf(s2, s3)) <= ms0) {
                    INSERT_RM(Ls0, Li0, ms0, mi0, s0, c0 + 0);
                    INSERT_RM(Ls0, Li0, ms0, mi0, s1, c0 + 1);
                    INSERT_RM(Ls0, Li0, ms0, mi0, s2, c0 + 2);
                    INSERT_RM(Ls0, Li0, ms0, mi0, s3, c0 + 3);
                }
            }
            {
                float s0 = acc1[cf][0], s1 = acc1[cf][1], s2 = acc1[cf][2], s3 = acc1[cf][3];
                if (fminf(fminf(s0, s1), fminf(s2, s3)) <= ms1) {
                    INSERT_RM(Ls1, Li1, ms1, mi1, s0, c0 + 0);
                    INSERT_RM(Ls1, Li1, ms1, mi1, s1, c0 + 1);
                    INSERT_RM(Ls1, Li1, ms1, mi1, s2, c0 + 2);
                    INSERT_RM(Ls1, Li1, ms1, mi1, s3, c0 + 3);
                }
            }
        }

        __syncthreads();   // single barrier per tile: drains prefetch + fences buf reuse
        buf ^= 1;
    }

    // ---- merge the 4 cand-partitions per row (snapshot butterfly over lk4) ----
#pragma unroll
    for (int mask = 16; mask <= 32; mask <<= 1) {
        float pd[TOPS]; int pi[TOPS];
#pragma unroll
        for (int e = 0; e < TOPS; ++e) {
            pd[e] = __shfl_xor(Ls0[e], mask, 64);
            pi[e] = __shfl_xor(Li0[e], mask, 64);
        }
#pragma unroll
        for (int e = 0; e < TOPS; ++e) INSERT_RM(Ls0, Li0, ms0, mi0, pd[e], pi[e]);
#pragma unroll
        for (int e = 0; e < TOPS; ++e) {
            pd[e] = __shfl_xor(Ls1[e], mask, 64);
            pi[e] = __shfl_xor(Li1[e], mask, 64);
        }
#pragma unroll
        for (int e = 0; e < TOPS; ++e) INSERT_RM(Ls1, Li1, ms1, mi1, pd[e], pi[e]);
    }

    if (lk4 == 0) {   // lanes 0..15: final per-strip top-7 for both owner rows
        const int row0 = qbase + w * 32 + lq16;
        ushort_t* dst0 = shortlist + (size_t)row0 * SLW + strip * TOPS;
        ushort_t* dst1 = shortlist + (size_t)(row0 + 16) * SLW + strip * TOPS;
#pragma unroll
        for (int e = 0; e < TOPS; ++e) { dst0[e] = (ushort_t)Li0[e]; dst1[e] = (ushort_t)Li1[e]; }
    }
}

// K2: exact fp32 rescore. One block per query row; 4 threads per candidate;
// exact (dist, idx) lexicographic top-5; label match; atomic count.
__global__ __launch_bounds__(256) void rescore_kernel(const float* __restrict__ emb,
                                                      const int* __restrict__ labels,
                                                      const float* __restrict__ norms,
                                                      const ushort_t* __restrict__ shortlist,
                                                      int* __restrict__ cnt) {
    __shared__ float qrow[DIM];
    __shared__ float ds[64];
    __shared__ int   di[64];
    const int q = blockIdx.x;
    const int tid = threadIdx.x;
    if (tid < 64)
        *reinterpret_cast<float4*>(qrow + tid * 4) =
            *reinterpret_cast<const float4*>(emb + (size_t)q * DIM + tid * 4);
    __syncthreads();

    const int cslot = tid >> 2, part = tid & 3;
    float dv = 3.0e38f; int civ = 0x7fffffff;
    if (cslot < SLW) {
        int c = shortlist[(size_t)q * SLW + cslot];
        if (c != q) {   // uniform within the 4-lane group -> shuffles are safe
            const float* crow = emb + (size_t)c * DIM + part * 64;
            const float* qr = qrow + part * 64;
            float p0 = 0.f, p1 = 0.f, p2 = 0.f, p3 = 0.f;
#pragma unroll
            for (int kk = 0; kk < 16; ++kk) {
                float4 cv = *reinterpret_cast<const float4*>(crow + kk * 4);
                float4 qv = *reinterpret_cast<const float4*>(qr + kk * 4);
                p0 = fmaf(cv.x, qv.x, p0); p1 = fmaf(cv.y, qv.y, p1);
                p2 = fmaf(cv.z, qv.z, p2); p3 = fmaf(cv.w, qv.w, p3);
            }
            float p = (p0 + p1) + (p2 + p3);
            p += __shfl_xor(p, 1, 64);
            p += __shfl_xor(p, 2, 64);
            if (part == 0) { dv = fmaf(-2.0f, p, norms[q] + norms[c]); civ = c; }
        }
    }
    if (part == 0) { ds[cslot] = dv; di[cslot] = civ; }
    __syncthreads();

    if (tid < 64) {
        float dl = ds[tid]; int il = di[tid];
        const int lq = labels[q];
        bool match = false;
#pragma unroll
        for (int r = 0; r < KNN; ++r) {
            float md = dl; int mx = il;
#pragma unroll
            for (int mask = 1; mask <= 32; mask <<= 1) {
                float pd = __shfl_xor(md, mask, 64);
                int   pi = __shfl_xor(mx, mask, 64);
                if (pd < md || (pd == md && pi < mx)) { md = pd; mx = pi; }
            }
            if (il == mx) dl = 3.0e38f;   // owner retires its candidate
            match = match || (labels[mx] == lq);
        }
        if (tid == 0) atomicAdd(cnt, match ? 1 : 0);
    }
}

// K3: scalar output = count / N (power-of-two divide, exact)
__global__ void finalize_kernel(const int* __restrict__ cnt, float* __restrict__ out) {
    if (threadIdx.x == 0) out[0] = (float)(*cnt) * (1.0f / (float)NPTS);
}

extern "C" void kernel_launch(void* const* d_in, const int* in_sizes, int n_in,
                              void* d_out, int out_size, void* d_ws, size_t ws_size,
                              hipStream_t stream) {
    (void)in_sizes; (void)n_in; (void)out_size; (void)ws_size;
    const float* emb    = (const float*)d_in[0];
    const int*   labels = (const int*)d_in[1];
    float*       out    = (float*)d_out;

    char* ws = (char*)d_ws;
    int*       cnt       = (int*)(ws + WS_CNT);
    float*     norms     = (float*)(ws + WS_NORMS);
    _Float16*  hiA       = (_Float16*)(ws + WS_HIA);
    ushort_t*  shortlist = (ushort_t*)(ws + WS_SL);

    prep_kernel<<<NPTS / 4, 256, 0, stream>>>(emb, norms, hiA, cnt);
    filter_kernel<<<(NPTS / RPB) * STRIPS, 256, 0, stream>>>(hiA, shortlist);
    rescore_kernel<<<NPTS, 256, 0, stream>>>(emb, labels, norms, shortlist, cnt);
    finalize_kernel<<<1, 64, 0, stream>>>(cnt, out);
}

// Round 8
// 546.483 us; speedup vs baseline: 2.6157x; 1.9001x over previous
//
#include <hip/hip_runtime.h>

#define NPTS 16384
#define DIM 256
#define NKC 36                 // augmented kchunks (8 halfs each): 32 data + (h,l) + pad
#define KNN 5
#define RPB 256                // rows per block = 8 waves x 32
#define CTILE 64               // candidates per tile
#define STRIPS 8
#define STRIP (NPTS / STRIPS)  // 2048
#define NCB (STRIP / CTILE)    // 32
#define TOPS 7                 // per-strip shortlist depth (self + 5 + 1 spare)
#define SLW (STRIPS * TOPS)    // 56 shortlist slots per row

typedef _Float16 f16x8 __attribute__((ext_vector_type(8)));
typedef float    f32x4 __attribute__((ext_vector_type(4)));
typedef unsigned short ushort_t;

// workspace byte offsets
#define WS_CNT   0
#define WS_NORMS 4096                          // float [NPTS]
#define WS_HIA   (WS_NORMS + NPTS * 4)         // _Float16 [NKC][NPTS][8] k-major
#define WS_SL    (WS_HIA + NPTS * NKC * 16)    // ushort [NPTS][SLW]

// compare-exchange on (val,idx) pairs (no tie-break needed in the filter:
// K2 re-ranks exactly; filter only needs the exact fp16-score top-7 SET)
#define CE(a, ia, b, ib) do {                                                 \
    bool c_ = (b) < (a);                                                      \
    float tv_ = c_ ? (a) : (b); (a) = c_ ? (b) : (a); (b) = tv_;              \
    int   ti_ = c_ ? (ia) : (ib); (ia) = c_ ? (ib) : (ia); (ib) = ti_;        \
} while (0)

// branch-free bubble insert into ascending sorted-7 (non-qualifier = no-op)
#define BUBBLE(Ls, Li, v, ix) do {                                            \
    float cv_ = (v); int ci_ = (ix);                                          \
    _Pragma("unroll")                                                         \
    for (int e_ = 0; e_ < TOPS; ++e_) {                                       \
        bool lt_ = cv_ < Ls[e_];                                              \
        float tv_ = lt_ ? Ls[e_] : cv_; Ls[e_] = lt_ ? cv_ : Ls[e_]; cv_ = tv_;\
        int ti_ = lt_ ? Li[e_] : ci_;  Li[e_] = lt_ ? ci_ : Li[e_]; ci_ = ti_;\
    } } while (0)

// K0: build k-major augmented fp16 candidate buffer hiA[kc][cand][8]:
// chunks 0..31 = -2*fp16(c), chunk 32 = [h,l,0...] (h+l ~= ||c||^2), 33..35 = 0.
__global__ __launch_bounds__(256) void prep_kernel(const float* __restrict__ emb,
                                                   float* __restrict__ norms,
                                                   _Float16* __restrict__ hiA,
                                                   int* __restrict__ cnt) {
    if (blockIdx.x == 0 && threadIdx.x == 0) *cnt = 0;
    const int row = blockIdx.x * 4 + (threadIdx.x >> 6);
    const int l   = threadIdx.x & 63;
    float4 v = *reinterpret_cast<const float4*>(emb + (size_t)row * DIM + l * 4);
    union { _Float16 h[4]; short4 s; } u;
    u.h[0] = (_Float16)v.x * (_Float16)-2.0f;
    u.h[1] = (_Float16)v.y * (_Float16)-2.0f;
    u.h[2] = (_Float16)v.z * (_Float16)-2.0f;
    u.h[3] = (_Float16)v.w * (_Float16)-2.0f;
    *reinterpret_cast<short4*>(hiA + ((size_t)(l >> 1) * NPTS + row) * 8 + (l & 1) * 4) = u.s;

    float s = v.x * v.x + v.y * v.y + v.z * v.z + v.w * v.w;
#pragma unroll
    for (int off = 32; off > 0; off >>= 1) s += __shfl_down(s, off, 64);
    float tot = __shfl(s, 0, 64);
    if (l == 0) norms[row] = tot;
    if (l < 4) {   // chunks 32..35
        union { _Float16 h[4]; short4 s; } z0, z1;
        z0.h[0] = (_Float16)0.f; z0.h[1] = (_Float16)0.f;
        z0.h[2] = (_Float16)0.f; z0.h[3] = (_Float16)0.f;
        z1 = z0;
        if (l == 0) {
            _Float16 hh = (_Float16)tot;
            _Float16 ll = (_Float16)(tot - (float)hh);
            z0.h[0] = hh; z0.h[1] = ll;
        }
        _Float16* dst = hiA + ((size_t)(32 + l) * NPTS + row) * 8;
        *reinterpret_cast<short4*>(dst)     = z0.s;
        *reinterpret_cast<short4*>(dst + 4) = z1.s;
    }
}

// K1: MFMA filter. Block = 8 waves x 256 rows x 2048-cand strip; wave = 32 rows.
// B (rows): full-K resident in registers/AGPRs (unified file), hiA * -0.5.
// A (cands): full-K 64-cand tiles in LDS, double-buffered, ONE barrier/tile.
// Epilogue: sort4 -> 2 unconditional sorted-bubble inserts + __any-guarded rest.
__global__ __launch_bounds__(512, 4) void filter_kernel(const _Float16* __restrict__ hiA,
                                                        ushort_t* __restrict__ shortlist) {
    __shared__ _Float16 At[2 * NKC * CTILE * 8];   // 73728 B
    const int tid  = threadIdx.x;
    const int w    = tid >> 6;        // wave 0..7
    const int l    = tid & 63;
    const int lq16 = l & 15;          // D col = query-row-in-16
    const int lk4  = l >> 4;          // k-quarter / cand sub-group
    const int panel = blockIdx.x >> 3;
    const int strip = blockIdx.x & 7; // native XCD slot -> strip slice L2-resident
    const int qbase = panel * RPB;
    const int cand0 = strip * STRIP;

    // ---- B fragments resident: 2 rf x 8 t (kc = t*4+lk4), coalesced loads ----
    const size_t r0 = (size_t)qbase + w * 32 + lq16;
    f16x8 breg0[8], breg1[8];
#pragma unroll
    for (int t = 0; t < 8; ++t) {
        f16x8 v0 = *reinterpret_cast<const f16x8*>(hiA + ((size_t)(t * 4 + lk4) * NPTS + r0) * 8);
        f16x8 v1 = *reinterpret_cast<const f16x8*>(hiA + ((size_t)(t * 4 + lk4) * NPTS + r0 + 16) * 8);
#pragma unroll
        for (int e = 0; e < 8; ++e) {   // -0.5 * (-2q) = q, exact in fp16
            v0[e] = v0[e] * (_Float16)-0.5f;
            v1[e] = v1[e] * (_Float16)-0.5f;
        }
        breg0[t] = v0; breg1[t] = v1;
    }
    f16x8 breg8 = 0;                    // augmented chunk: [1,1,0..] on quarter 0
    if (lk4 == 0) { breg8[0] = (_Float16)1.0f; breg8[1] = (_Float16)1.0f; }

    // sorted ascending top-7 per rf
    float Ls0[TOPS], Ls1[TOPS]; int Li0[TOPS], Li1[TOPS];
#pragma unroll
    for (int e = 0; e < TOPS; ++e) {
        Ls0[e] = 3.0e38f; Li0[e] = 0x7fffffff;
        Ls1[e] = 3.0e38f; Li1[e] = 0x7fffffff;
    }

    // ---- staging: 4 full rounds + 1 half round (36864 B, 512 thr x 16 B) ----
#define STAGE(bufoff, cb_) do {                                               \
    const int cbn_ = cand0 + (cb_) * CTILE;                                   \
    _Pragma("unroll")                                                         \
    for (int i_ = 0; i_ < 4; ++i_) {                                          \
        int d_ = i_ * 8192 + tid * 16;                                        \
        int kc_ = d_ >> 10, cd_ = (d_ >> 4) & 63;                             \
        const _Float16* g_ = hiA + ((size_t)kc_ * NPTS + cbn_ + cd_) * 8;     \
        __builtin_amdgcn_global_load_lds(                                     \
            (const __attribute__((address_space(1))) void*)g_,                \
            (__attribute__((address_space(3))) void*)((char*)At + (bufoff) + d_), 16, 0, 0); \
    }                                                                         \
    if (tid < 256) {                                                          \
        int d_ = 32768 + tid * 16;                                            \
        int kc_ = d_ >> 10, cd_ = (d_ >> 4) & 63;                             \
        const _Float16* g_ = hiA + ((size_t)kc_ * NPTS + cbn_ + cd_) * 8;     \
        __builtin_amdgcn_global_load_lds(                                     \
            (const __attribute__((address_space(1))) void*)g_,                \
            (__attribute__((address_space(3))) void*)((char*)At + (bufoff) + d_), 16, 0, 0); \
    } } while (0)

    STAGE(0, 0);
    __syncthreads();

    int buf = 0;
    for (int cb = 0; cb < NCB; ++cb) {
        if (cb + 1 < NCB) STAGE((buf ^ 1) * 36864, cb + 1);   // lands under compute

        // compute: 9 k-steps x 4 cf x 2 rf = 72 MFMAs, no barriers inside
        const char* Ab = (const char*)At + buf * 36864;
        f32x4 acc0[4], acc1[4];
#pragma unroll
        for (int cf = 0; cf < 4; ++cf) {
            acc0[cf] = (f32x4){0.f, 0.f, 0.f, 0.f};
            acc1[cf] = (f32x4){0.f, 0.f, 0.f, 0.f};
        }
#pragma unroll
        for (int t = 0; t < 9; ++t) {
            f16x8 bf0 = (t < 8) ? breg0[t] : breg8;
            f16x8 bf1 = (t < 8) ? breg1[t] : breg8;
#pragma unroll
            for (int cf = 0; cf < 4; ++cf) {
                f16x8 af = *reinterpret_cast<const f16x8*>(
                    Ab + (size_t)((t * 4 + lk4) * 64 + cf * 16 + lq16) * 16);
                acc0[cf] = __builtin_amdgcn_mfma_f32_16x16x32_f16(af, bf0, acc0[cf], 0, 0, 0);
                acc1[cf] = __builtin_amdgcn_mfma_f32_16x16x32_f16(af, bf1, acc1[cf], 0, 0, 0);
            }
        }

        // epilogue: per cf-rf block, sort4 -> insert 2 smallest, guard the rest
        const int cbase = cand0 + cb * CTILE;
#pragma unroll
        for (int cf = 0; cf < 4; ++cf) {
            const int c0 = cbase + cf * 16 + (lk4 << 2);
            {
                float v0 = acc0[cf][0], v1 = acc0[cf][1], v2 = acc0[cf][2], v3 = acc0[cf][3];
                int i0 = c0, i1 = c0 + 1, i2 = c0 + 2, i3 = c0 + 3;
                CE(v0, i0, v1, i1); CE(v2, i2, v3, i3);
                CE(v0, i0, v2, i2); CE(v1, i1, v3, i3); CE(v1, i1, v2, i2);
                BUBBLE(Ls0, Li0, v0, i0);
                BUBBLE(Ls0, Li0, v1, i1);
                if (__any(v2 < Ls0[TOPS - 1])) {       // rare: >=3 qualifiers
                    BUBBLE(Ls0, Li0, v2, i2);
                    if (__any(v3 < Ls0[TOPS - 1])) BUBBLE(Ls0, Li0, v3, i3);
                }
            }
            {
                float v0 = acc1[cf][0], v1 = acc1[cf][1], v2 = acc1[cf][2], v3 = acc1[cf][3];
                int i0 = c0, i1 = c0 + 1, i2 = c0 + 2, i3 = c0 + 3;
                CE(v0, i0, v1, i1); CE(v2, i2, v3, i3);
                CE(v0, i0, v2, i2); CE(v1, i1, v3, i3); CE(v1, i1, v2, i2);
                BUBBLE(Ls1, Li1, v0, i0);
                BUBBLE(Ls1, Li1, v1, i1);
                if (__any(v2 < Ls1[TOPS - 1])) {
                    BUBBLE(Ls1, Li1, v2, i2);
                    if (__any(v3 < Ls1[TOPS - 1])) BUBBLE(Ls1, Li1, v3, i3);
                }
            }
        }

        __syncthreads();   // single barrier/tile: drains prefetch + fences buf reuse
        buf ^= 1;
    }

    // ---- merge the 4 cand-partitions per row (snapshot butterfly over lk4) ----
#pragma unroll
    for (int mask = 16; mask <= 32; mask <<= 1) {
        float pd[TOPS]; int pi[TOPS];
#pragma unroll
        for (int e = 0; e < TOPS; ++e) {
            pd[e] = __shfl_xor(Ls0[e], mask, 64);
            pi[e] = __shfl_xor(Li0[e], mask, 64);
        }
#pragma unroll
        for (int e = 0; e < TOPS; ++e) BUBBLE(Ls0, Li0, pd[e], pi[e]);
#pragma unroll
        for (int e = 0; e < TOPS; ++e) {
            pd[e] = __shfl_xor(Ls1[e], mask, 64);
            pi[e] = __shfl_xor(Li1[e], mask, 64);
        }
#pragma unroll
        for (int e = 0; e < TOPS; ++e) BUBBLE(Ls1, Li1, pd[e], pi[e]);
    }

    if (lk4 == 0) {   // lanes 0..15: final per-strip top-7 for both owner rows
        ushort_t* dst0 = shortlist + r0 * SLW + strip * TOPS;
        ushort_t* dst1 = shortlist + (r0 + 16) * SLW + strip * TOPS;
#pragma unroll
        for (int e = 0; e < TOPS; ++e) { dst0[e] = (ushort_t)Li0[e]; dst1[e] = (ushort_t)Li1[e]; }
    }
#undef STAGE
}

// K2: exact fp32 rescore of the 56 shortlisted candidates per row; 4 threads
// per candidate; exact (dist, idx) lexicographic top-5; label match; count.
__global__ __launch_bounds__(256) void rescore_kernel(const float* __restrict__ emb,
                                                      const int* __restrict__ labels,
                                                      const float* __restrict__ norms,
                                                      const ushort_t* __restrict__ shortlist,
                                                      int* __restrict__ cnt) {
    __shared__ float qrow[DIM];
    __shared__ float ds[64];
    __shared__ int   di[64];
    const int q = blockIdx.x;
    const int tid = threadIdx.x;
    if (tid < 64)
        *reinterpret_cast<float4*>(qrow + tid * 4) =
            *reinterpret_cast<const float4*>(emb + (size_t)q * DIM + tid * 4);
    __syncthreads();

    const int cslot = tid >> 2, part = tid & 3;
    float dv = 3.0e38f; int civ = 0x7fffffff;
    if (cslot < SLW) {
        int c = shortlist[(size_t)q * SLW + cslot];
        if (c != q) {   // uniform within the 4-lane group -> shuffles are safe
            const float* crow = emb + (size_t)c * DIM + part * 64;
            const float* qr = qrow + part * 64;
            float p0 = 0.f, p1 = 0.f, p2 = 0.f, p3 = 0.f;
#pragma unroll
            for (int kk = 0; kk < 16; ++kk) {
                float4 cv = *reinterpret_cast<const float4*>(crow + kk * 4);
                float4 qv = *reinterpret_cast<const float4*>(qr + kk * 4);
                p0 = fmaf(cv.x, qv.x, p0); p1 = fmaf(cv.y, qv.y, p1);
                p2 = fmaf(cv.z, qv.z, p2); p3 = fmaf(cv.w, qv.w, p3);
            }
            float p = (p0 + p1) + (p2 + p3);
            p += __shfl_xor(p, 1, 64);
            p += __shfl_xor(p, 2, 64);
            if (part == 0) { dv = fmaf(-2.0f, p, norms[q] + norms[c]); civ = c; }
        }
    }
    if (part == 0) { ds[cslot] = dv; di[cslot] = civ; }
    __syncthreads();

    if (tid < 64) {
        float dl = ds[tid]; int il = di[tid];
        const int lq = labels[q];
        bool match = false;
#pragma unroll
        for (int r = 0; r < KNN; ++r) {
            float md = dl; int mx = il;
#pragma unroll
            for (int mask = 1; mask <= 32; mask <<= 1) {
                float pd = __shfl_xor(md, mask, 64);
                int   pi = __shfl_xor(mx, mask, 64);
                if (pd < md || (pd == md && pi < mx)) { md = pd; mx = pi; }
            }
            if (il == mx) dl = 3.0e38f;   // owner retires its candidate
            match = match || (labels[mx] == lq);
        }
        if (tid == 0) atomicAdd(cnt, match ? 1 : 0);
    }
}

// K3: scalar output = count / N (power-of-two divide, exact)
__global__ void finalize_kernel(const int* __restrict__ cnt, float* __restrict__ out) {
    if (threadIdx.x == 0) out[0] = (float)(*cnt) * (1.0f / (float)NPTS);
}

extern "C" void kernel_launch(void* const* d_in, const int* in_sizes, int n_in,
                              void* d_out, int out_size, void* d_ws, size_t ws_size,
                              hipStream_t stream) {
    (void)in_sizes; (void)n_in; (void)out_size; (void)ws_size;
    const float* emb    = (const float*)d_in[0];
    const int*   labels = (const int*)d_in[1];
    float*       out    = (float*)d_out;

    char* ws = (char*)d_ws;
    int*       cnt       = (int*)(ws + WS_CNT);
    float*     norms     = (float*)(ws + WS_NORMS);
    _Float16*  hiA       = (_Float16*)(ws + WS_HIA);
    ushort_t*  shortlist = (ushort_t*)(ws + WS_SL);

    prep_kernel<<<NPTS / 4, 256, 0, stream>>>(emb, norms, hiA, cnt);
    filter_kernel<<<(NPTS / RPB) * STRIPS, 512, 0, stream>>>(hiA, shortlist);
    rescore_kernel<<<NPTS, 256, 0, stream>>>(emb, labels, norms, shortlist, cnt);
    finalize_kernel<<<1, 64, 0, stream>>>(cnt, out);
}

// Round 9
// 441.329 us; speedup vs baseline: 3.2389x; 1.2383x over previous
//
#include <hip/hip_runtime.h>

#define NPTS 16384
#define DIM 256
#define NKC 36                 // augmented kchunks: 32 data + [hc,lc] + [1,1,2] + 2 pad
#define KNN 5
#define RPB 256                // rows per block = 8 waves x 32
#define CTILE 64               // candidates per tile
#define STRIPS 8
#define STRIP (NPTS / STRIPS)  // 2048
#define NCB (STRIP / CTILE)    // 32
#define TOPS 7                 // per-strip shortlist depth (self + 5 + 1 spare)
#define SLW (STRIPS * TOPS)    // 56 shortlist slots per row
#define SEL 16                 // candidates rescored exactly per row

typedef _Float16 f16x8 __attribute__((ext_vector_type(8)));
typedef float    f32x4 __attribute__((ext_vector_type(4)));

// workspace byte offsets
#define WS_CNT   0
#define WS_NORMS 4096                          // float [NPTS]
#define WS_HIA   (WS_NORMS + NPTS * 4)         // _Float16 [NKC][NPTS][8] k-major
#define WS_SL    (WS_HIA + NPTS * NKC * 16)    // unsigned [NPTS][SLW]

// pack positive fp16 score + 14-bit idx into one sortable u32
__device__ __forceinline__ unsigned packsi(float s, int idx) {
    union { _Float16 h; unsigned short u; } cv;
    cv.h = (_Float16)s;                       // RNE, score > 0 by construction
    return ((unsigned)cv.u << 16) | (unsigned)idx;
}

// compare-exchange (min/max) on packed u32 — 2 VALU ops, idx travels free
#define CEU(a, b) do {                                                        \
    unsigned mn_ = (a) < (b) ? (a) : (b);                                     \
    unsigned mx_ = (a) < (b) ? (b) : (a);                                     \
    (a) = mn_; (b) = mx_;                                                     \
} while (0)

// bubble x into ascending sorted TOPS-list of packed u32 (no-op if too big)
#define BUBBLE_U(Lp, x) do {                                                  \
    unsigned c_ = (x);                                                        \
    _Pragma("unroll")                                                         \
    for (int e_ = 0; e_ < TOPS; ++e_) {                                       \
        unsigned mn_ = c_ < Lp[e_] ? c_ : Lp[e_];                             \
        unsigned mx_ = c_ < Lp[e_] ? Lp[e_] : c_;                             \
        Lp[e_] = mn_; c_ = mx_;                                               \
    } } while (0)

// K0: k-major augmented fp16 buffer hiA[kc][row][8]:
// kc 0..31 = -2*fp16(row), kc32 = [h,l,0..] (h+l ~= ||row||^2),
// kc33 = [1,1,2,0..] (constant), kc34/35 = 0. Plus fp32 norms, counter=0.
__global__ __launch_bounds__(256) void prep_kernel(const float* __restrict__ emb,
                                                   float* __restrict__ norms,
                                                   _Float16* __restrict__ hiA,
                                                   int* __restrict__ cnt) {
    if (blockIdx.x == 0 && threadIdx.x == 0) *cnt = 0;
    const int row = blockIdx.x * 4 + (threadIdx.x >> 6);
    const int l   = threadIdx.x & 63;
    float4 v = *reinterpret_cast<const float4*>(emb + (size_t)row * DIM + l * 4);
    union { _Float16 h[4]; short4 s; } u;
    u.h[0] = (_Float16)v.x * (_Float16)-2.0f;
    u.h[1] = (_Float16)v.y * (_Float16)-2.0f;
    u.h[2] = (_Float16)v.z * (_Float16)-2.0f;
    u.h[3] = (_Float16)v.w * (_Float16)-2.0f;
    *reinterpret_cast<short4*>(hiA + ((size_t)(l >> 1) * NPTS + row) * 8 + (l & 1) * 4) = u.s;

    float s = v.x * v.x + v.y * v.y + v.z * v.z + v.w * v.w;
#pragma unroll
    for (int off = 32; off > 0; off >>= 1) s += __shfl_down(s, off, 64);
    float tot = __shfl(s, 0, 64);
    if (l == 0) norms[row] = tot;
    if (l < 4) {   // chunks 32..35
        union { _Float16 h[4]; short4 s; } z0, z1;
        z0.h[0] = (_Float16)0.f; z0.h[1] = (_Float16)0.f;
        z0.h[2] = (_Float16)0.f; z0.h[3] = (_Float16)0.f;
        z1 = z0;
        if (l == 0) {
            _Float16 hh = (_Float16)tot;
            _Float16 ll = (_Float16)(tot - (float)hh);
            z0.h[0] = hh; z0.h[1] = ll;
        }
        if (l == 1) {   // A-side of the +||q||^2+4 fold
            z0.h[0] = (_Float16)1.0f; z0.h[1] = (_Float16)1.0f; z0.h[2] = (_Float16)2.0f;
        }
        _Float16* dst = hiA + ((size_t)(32 + l) * NPTS + row) * 8;
        *reinterpret_cast<short4*>(dst)     = z0.s;
        *reinterpret_cast<short4*>(dst + 4) = z1.s;
    }
}

// K1: MFMA filter (r8 geometry). score = dist(q,c)+4 > 0 straight from MFMA.
// Lists are packed u32 -> min/max-only maintenance.
__global__ __launch_bounds__(512, 4) void filter_kernel(const _Float16* __restrict__ hiA,
                                                        unsigned* __restrict__ shortlist) {
    __shared__ _Float16 At[2 * NKC * CTILE * 8];   // 73728 B
    const int tid  = threadIdx.x;
    const int w    = tid >> 6;        // wave 0..7
    const int l    = tid & 63;
    const int lq16 = l & 15;          // D col = query-row-in-16
    const int lk4  = l >> 4;          // k-quarter / cand sub-group
    const int panel = blockIdx.x >> 3;
    const int strip = blockIdx.x & 7; // native XCD slot -> strip slice L2-resident
    const int qbase = panel * RPB;
    const int cand0 = strip * STRIP;

    // ---- B fragments resident: 2 rf x 8 t (kc = t*4+lk4), coalesced loads ----
    const size_t r0 = (size_t)qbase + w * 32 + lq16;
    f16x8 breg0[8], breg1[8];
#pragma unroll
    for (int t = 0; t < 8; ++t) {
        f16x8 v0 = *reinterpret_cast<const f16x8*>(hiA + ((size_t)(t * 4 + lk4) * NPTS + r0) * 8);
        f16x8 v1 = *reinterpret_cast<const f16x8*>(hiA + ((size_t)(t * 4 + lk4) * NPTS + r0 + 16) * 8);
#pragma unroll
        for (int e = 0; e < 8; ++e) {   // -0.5 * (-2q) = q, exact in fp16
            v0[e] = v0[e] * (_Float16)-0.5f;
            v1[e] = v1[e] * (_Float16)-0.5f;
        }
        breg0[t] = v0; breg1[t] = v1;
    }
    // augmented k-step (t=8): lk4=0 -> [1,1,0..] (picks hc+lc);
    // lk4=1 -> [hq,lq,2,0..] (picks hq+lq+4 against A's [1,1,2]); else 0.
    f16x8 b8_0 = 0, b8_1 = 0;
    {
        f16x8 raw0 = *reinterpret_cast<const f16x8*>(hiA + ((size_t)32 * NPTS + r0) * 8);
        f16x8 raw1 = *reinterpret_cast<const f16x8*>(hiA + ((size_t)32 * NPTS + r0 + 16) * 8);
        if (lk4 == 0) {
            b8_0[0] = (_Float16)1.0f; b8_0[1] = (_Float16)1.0f;
            b8_1[0] = (_Float16)1.0f; b8_1[1] = (_Float16)1.0f;
        } else if (lk4 == 1) {
            b8_0 = raw0; b8_0[2] = (_Float16)2.0f;
            b8_1 = raw1; b8_1[2] = (_Float16)2.0f;
        }
    }

    // ascending sorted top-7, packed u32
    unsigned Lp0[TOPS], Lp1[TOPS];
#pragma unroll
    for (int e = 0; e < TOPS; ++e) { Lp0[e] = 0xFFFFFFFFu; Lp1[e] = 0xFFFFFFFFu; }

#define STAGE(bufoff, cb_) do {                                               \
    const int cbn_ = cand0 + (cb_) * CTILE;                                   \
    _Pragma("unroll")                                                         \
    for (int i_ = 0; i_ < 4; ++i_) {                                          \
        int d_ = i_ * 8192 + tid * 16;                                        \
        int kc_ = d_ >> 10, cd_ = (d_ >> 4) & 63;                             \
        const _Float16* g_ = hiA + ((size_t)kc_ * NPTS + cbn_ + cd_) * 8;     \
        __builtin_amdgcn_global_load_lds(                                     \
            (const __attribute__((address_space(1))) void*)g_,                \
            (__attribute__((address_space(3))) void*)((char*)At + (bufoff) + d_), 16, 0, 0); \
    }                                                                         \
    if (tid < 256) {                                                          \
        int d_ = 32768 + tid * 16;                                            \
        int kc_ = d_ >> 10, cd_ = (d_ >> 4) & 63;                             \
        const _Float16* g_ = hiA + ((size_t)kc_ * NPTS + cbn_ + cd_) * 8;     \
        __builtin_amdgcn_global_load_lds(                                     \
            (const __attribute__((address_space(1))) void*)g_,                \
            (__attribute__((address_space(3))) void*)((char*)At + (bufoff) + d_), 16, 0, 0); \
    } } while (0)

    STAGE(0, 0);
    __syncthreads();

    int buf = 0;
    for (int cb = 0; cb < NCB; ++cb) {
        if (cb + 1 < NCB) STAGE((buf ^ 1) * 36864, cb + 1);   // lands under compute

        // compute: 9 k-steps x 4 cf x 2 rf = 72 MFMAs, no barriers inside
        const char* Ab = (const char*)At + buf * 36864;
        f32x4 acc0[4], acc1[4];
#pragma unroll
        for (int cf = 0; cf < 4; ++cf) {
            acc0[cf] = (f32x4){0.f, 0.f, 0.f, 0.f};
            acc1[cf] = (f32x4){0.f, 0.f, 0.f, 0.f};
        }
#pragma unroll
        for (int t = 0; t < 9; ++t) {
            f16x8 bf0 = (t < 8) ? breg0[t] : b8_0;
            f16x8 bf1 = (t < 8) ? breg1[t] : b8_1;
#pragma unroll
            for (int cf = 0; cf < 4; ++cf) {
                f16x8 af = *reinterpret_cast<const f16x8*>(
                    Ab + (size_t)((t * 4 + lk4) * 64 + cf * 16 + lq16) * 16);
                acc0[cf] = __builtin_amdgcn_mfma_f32_16x16x32_f16(af, bf0, acc0[cf], 0, 0, 0);
                acc1[cf] = __builtin_amdgcn_mfma_f32_16x16x32_f16(af, bf1, acc1[cf], 0, 0, 0);
            }
        }

        // epilogue: pack -> u32 sort4 -> 2 unconditional bubbles + guarded rest
        const int cbase = cand0 + cb * CTILE;
#pragma unroll
        for (int cf = 0; cf < 4; ++cf) {
            const int c0 = cbase + cf * 16 + (lk4 << 2);
            {
                unsigned p0 = packsi(acc0[cf][0], c0 + 0);
                unsigned p1 = packsi(acc0[cf][1], c0 + 1);
                unsigned p2 = packsi(acc0[cf][2], c0 + 2);
                unsigned p3 = packsi(acc0[cf][3], c0 + 3);
                CEU(p0, p1); CEU(p2, p3); CEU(p0, p2); CEU(p1, p3); CEU(p1, p2);
                BUBBLE_U(Lp0, p0);
                BUBBLE_U(Lp0, p1);
                if (__any(p2 < Lp0[TOPS - 1])) {
                    BUBBLE_U(Lp0, p2);
                    if (__any(p3 < Lp0[TOPS - 1])) BUBBLE_U(Lp0, p3);
                }
            }
            {
                unsigned p0 = packsi(acc1[cf][0], c0 + 0);
                unsigned p1 = packsi(acc1[cf][1], c0 + 1);
                unsigned p2 = packsi(acc1[cf][2], c0 + 2);
                unsigned p3 = packsi(acc1[cf][3], c0 + 3);
                CEU(p0, p1); CEU(p2, p3); CEU(p0, p2); CEU(p1, p3); CEU(p1, p2);
                BUBBLE_U(Lp1, p0);
                BUBBLE_U(Lp1, p1);
                if (__any(p2 < Lp1[TOPS - 1])) {
                    BUBBLE_U(Lp1, p2);
                    if (__any(p3 < Lp1[TOPS - 1])) BUBBLE_U(Lp1, p3);
                }
            }
        }

        __syncthreads();   // single barrier/tile: drains prefetch + fences buf reuse
        buf ^= 1;
    }
#undef STAGE

    // ---- merge the 4 cand-partitions per row (snapshot butterfly over lk4) ----
#pragma unroll
    for (int mask = 16; mask <= 32; mask <<= 1) {
        unsigned pd[TOPS];
#pragma unroll
        for (int e = 0; e < TOPS; ++e)
            pd[e] = (unsigned)__shfl_xor((int)Lp0[e], mask, 64);
#pragma unroll
        for (int e = 0; e < TOPS; ++e) BUBBLE_U(Lp0, pd[e]);
#pragma unroll
        for (int e = 0; e < TOPS; ++e)
            pd[e] = (unsigned)__shfl_xor((int)Lp1[e], mask, 64);
#pragma unroll
        for (int e = 0; e < TOPS; ++e) BUBBLE_U(Lp1, pd[e]);
    }

    if (lk4 == 0) {   // lanes 0..15: final per-strip packed top-7 for both rows
        unsigned* dst0 = shortlist + r0 * SLW + strip * TOPS;
        unsigned* dst1 = shortlist + (r0 + 16) * SLW + strip * TOPS;
#pragma unroll
        for (int e = 0; e < TOPS; ++e) { dst0[e] = Lp0[e]; dst1[e] = Lp1[e]; }
    }
}

// K2: per row (one wave): bitonic-sort the 56 packed survivors across lanes,
// take the 16 lex-smallest, gather + exact fp32 rescore (4 lanes/cand),
// exact (dist, idx) lexicographic top-5, label match, atomic count.
__global__ __launch_bounds__(256) void rescore_kernel(const float* __restrict__ emb,
                                                      const int* __restrict__ labels,
                                                      const float* __restrict__ norms,
                                                      const unsigned* __restrict__ shortlist,
                                                      int* __restrict__ cnt) {
    __shared__ float qrow[4][DIM];
    const int tid = threadIdx.x;
    const int w = tid >> 6, l = tid & 63;
    const int q = blockIdx.x * 4 + w;

    *reinterpret_cast<float4*>(&qrow[w][l * 4]) =
        *reinterpret_cast<const float4*>(emb + (size_t)q * DIM + l * 4);

    unsigned v = 0xFFFFFFFFu;
    if (l < SLW) v = shortlist[(size_t)q * SLW + l];
    __syncthreads();

    // 64-lane bitonic sort ascending (packed u32; 8 pad lanes sort last)
#pragma unroll
    for (int k = 2; k <= 64; k <<= 1) {
#pragma unroll
        for (int j = k >> 1; j > 0; j >>= 1) {
            unsigned o = (unsigned)__shfl_xor((int)v, j, 64);
            bool keepmin = (((l & j) == 0) == ((l & k) == 0));
            unsigned mn = v < o ? v : o;
            unsigned mx = v < o ? o : v;
            v = keepmin ? mn : mx;
        }
    }

    const int cslot = l >> 2, part = l & 3;       // 16 cands x 4 lanes
    unsigned sel = (unsigned)__shfl((int)v, cslot, 64);
    int ci = (int)(sel & 0xFFFFu);

    float dv = 3.0e38f; int civ = 0x7fffffff;
    {
        const float* crow = emb + (size_t)ci * DIM + part * 64;
        const float* qr = &qrow[w][part * 64];
        float p0 = 0.f, p1 = 0.f, p2 = 0.f, p3 = 0.f;
#pragma unroll
        for (int kk = 0; kk < 16; ++kk) {
            float4 cv4 = *reinterpret_cast<const float4*>(crow + kk * 4);
            float4 qv4 = *reinterpret_cast<const float4*>(qr + kk * 4);
            p0 = fmaf(cv4.x, qv4.x, p0); p1 = fmaf(cv4.y, qv4.y, p1);
            p2 = fmaf(cv4.z, qv4.z, p2); p3 = fmaf(cv4.w, qv4.w, p3);
        }
        float p = (p0 + p1) + (p2 + p3);
        p += __shfl_xor(p, 1, 64);
        p += __shfl_xor(p, 2, 64);
        if (part == 0 && ci != q) { dv = fmaf(-2.0f, p, norms[q] + norms[ci]); civ = ci; }
    }

    const int lq = labels[q];
    bool match = false;
#pragma unroll
    for (int r = 0; r < KNN; ++r) {
        float md = dv; int mxi = civ;
#pragma unroll
        for (int mask = 1; mask <= 32; mask <<= 1) {
            float pd = __shfl_xor(md, mask, 64);
            int   pi = __shfl_xor(mxi, mask, 64);
            if (pd < md || (pd == md && pi < mxi)) { md = pd; mxi = pi; }
        }
        if (civ == mxi) dv = 3.0e38f;   // owner retires its candidate
        match = match || (labels[mxi] == lq);
    }
    if (l == 0) atomicAdd(cnt, match ? 1 : 0);
}

// K3: scalar output = count / N (power-of-two divide, exact)
__global__ void finalize_kernel(const int* __restrict__ cnt, float* __restrict__ out) {
    if (threadIdx.x == 0) out[0] = (float)(*cnt) * (1.0f / (float)NPTS);
}

extern "C" void kernel_launch(void* const* d_in, const int* in_sizes, int n_in,
                              void* d_out, int out_size, void* d_ws, size_t ws_size,
                              hipStream_t stream) {
    (void)in_sizes; (void)n_in; (void)out_size; (void)ws_size;
    const float* emb    = (const float*)d_in[0];
    const int*   labels = (const int*)d_in[1];
    float*       out    = (float*)d_out;

    char* ws = (char*)d_ws;
    int*       cnt       = (int*)(ws + WS_CNT);
    float*     norms     = (float*)(ws + WS_NORMS);
    _Float16*  hiA       = (_Float16*)(ws + WS_HIA);
    unsigned*  shortlist = (unsigned*)(ws + WS_SL);

    prep_kernel<<<NPTS / 4, 256, 0, stream>>>(emb, norms, hiA, cnt);
    filter_kernel<<<(NPTS / RPB) * STRIPS, 512, 0, stream>>>(hiA, shortlist);
    rescore_kernel<<<NPTS / 4, 256, 0, stream>>>(emb, labels, norms, shortlist, cnt);
    finalize_kernel<<<1, 64, 0, stream>>>(cnt, out);
}

// Round 10
// 418.326 us; speedup vs baseline: 3.4170x; 1.0550x over previous
//
#include <hip/hip_runtime.h>

#define NPTS 16384
#define DIM 256
#define NKC 36                 // augmented kchunks: 32 data + [hc,lc] + [1,1,2] + 2 pad
#define KNN 5
#define RPB 256                // rows per block = 8 waves x 32
#define CTILE 64               // candidates per tile
#define STRIPS 8
#define STRIP (NPTS / STRIPS)  // 2048
#define NCB (STRIP / CTILE)    // 32
#define TOPS 7                 // per-strip shortlist depth (self + 5 + 1 spare)
#define SLW (STRIPS * TOPS)    // 56 shortlist slots per row
#define SEL 16                 // candidates rescored exactly per row

typedef _Float16 f16x8 __attribute__((ext_vector_type(8)));
typedef float    f32x4 __attribute__((ext_vector_type(4)));

// workspace byte offsets
#define WS_CNT   0
#define WS_NORMS 4096                          // float [NPTS]
#define WS_HIA   (WS_NORMS + NPTS * 4)         // _Float16 [NKC][NPTS][8] k-major
#define WS_SL    (WS_HIA + NPTS * NKC * 16)    // unsigned [NPTS][SLW]

// pack positive fp16 score + 14-bit idx into one sortable u32
__device__ __forceinline__ unsigned packsi(float s, int idx) {
    union { _Float16 h; unsigned short u; } cv;
    cv.h = (_Float16)s;                       // RNE, score > 0 by construction
    return ((unsigned)cv.u << 16) | (unsigned)idx;
}

// compare-exchange (min/max) on packed u32 — 2 VALU ops, idx travels free
#define CEU(a, b) do {                                                        \
    unsigned mn_ = (a) < (b) ? (a) : (b);                                     \
    unsigned mx_ = (a) < (b) ? (b) : (a);                                     \
    (a) = mn_; (b) = mx_;                                                     \
} while (0)

// bubble x into ascending sorted TOPS-list of packed u32 (no-op if too big)
#define BUBBLE_U(Lp, x) do {                                                  \
    unsigned c_ = (x);                                                        \
    _Pragma("unroll")                                                         \
    for (int e_ = 0; e_ < TOPS; ++e_) {                                       \
        unsigned mn_ = c_ < Lp[e_] ? c_ : Lp[e_];                             \
        unsigned mx_ = c_ < Lp[e_] ? Lp[e_] : c_;                             \
        Lp[e_] = mn_; c_ = mx_;                                               \
    } } while (0)

// K0: k-major augmented fp16 buffer hiA[kc][row][8]:
// kc 0..31 = -2*fp16(row), kc32 = [h,l,0..] (h+l ~= ||row||^2),
// kc33 = [1,1,2,0..] (constant), kc34/35 = 0. Plus fp32 norms, counter=0.
__global__ __launch_bounds__(256) void prep_kernel(const float* __restrict__ emb,
                                                   float* __restrict__ norms,
                                                   _Float16* __restrict__ hiA,
                                                   int* __restrict__ cnt) {
    if (blockIdx.x == 0 && threadIdx.x == 0) *cnt = 0;
    const int row = blockIdx.x * 4 + (threadIdx.x >> 6);
    const int l   = threadIdx.x & 63;
    float4 v = *reinterpret_cast<const float4*>(emb + (size_t)row * DIM + l * 4);
    union { _Float16 h[4]; short4 s; } u;
    u.h[0] = (_Float16)v.x * (_Float16)-2.0f;
    u.h[1] = (_Float16)v.y * (_Float16)-2.0f;
    u.h[2] = (_Float16)v.z * (_Float16)-2.0f;
    u.h[3] = (_Float16)v.w * (_Float16)-2.0f;
    *reinterpret_cast<short4*>(hiA + ((size_t)(l >> 1) * NPTS + row) * 8 + (l & 1) * 4) = u.s;

    float s = v.x * v.x + v.y * v.y + v.z * v.z + v.w * v.w;
#pragma unroll
    for (int off = 32; off > 0; off >>= 1) s += __shfl_down(s, off, 64);
    float tot = __shfl(s, 0, 64);
    if (l == 0) norms[row] = tot;
    if (l < 4) {   // chunks 32..35
        union { _Float16 h[4]; short4 s; } z0, z1;
        z0.h[0] = (_Float16)0.f; z0.h[1] = (_Float16)0.f;
        z0.h[2] = (_Float16)0.f; z0.h[3] = (_Float16)0.f;
        z1 = z0;
        if (l == 0) {
            _Float16 hh = (_Float16)tot;
            _Float16 ll = (_Float16)(tot - (float)hh);
            z0.h[0] = hh; z0.h[1] = ll;
        }
        if (l == 1) {   // A-side of the +||q||^2+4 fold
            z0.h[0] = (_Float16)1.0f; z0.h[1] = (_Float16)1.0f; z0.h[2] = (_Float16)2.0f;
        }
        _Float16* dst = hiA + ((size_t)(32 + l) * NPTS + row) * 8;
        *reinterpret_cast<short4*>(dst)     = z0.s;
        *reinterpret_cast<short4*>(dst + 4) = z1.s;
    }
}

// K1: MFMA filter (r9 geometry + tile ROTATION for L2 reuse).
// score = dist(q,c)+4 > 0 straight from MFMA; packed-u32 list maintenance.
__global__ __launch_bounds__(512, 4) void filter_kernel(const _Float16* __restrict__ hiA,
                                                        unsigned* __restrict__ shortlist) {
    __shared__ _Float16 At[2 * NKC * CTILE * 8];   // 73728 B
    const int tid  = threadIdx.x;
    const int w    = tid >> 6;        // wave 0..7
    const int l    = tid & 63;
    const int lq16 = l & 15;          // D col = query-row-in-16
    const int lk4  = l >> 4;          // k-quarter / cand sub-group
    const int panel = blockIdx.x >> 3;
    const int strip = blockIdx.x & 7; // native XCD slot -> strip slice L2-resident
    const int qbase = panel * RPB;
    const int cand0 = strip * STRIP;
    const int rot   = panel & (NCB - 1);   // phase-decorrelated tile start

    // ---- B fragments resident: 2 rf x 8 t (kc = t*4+lk4), coalesced loads ----
    const size_t r0 = (size_t)qbase + w * 32 + lq16;
    f16x8 breg0[8], breg1[8];
#pragma unroll
    for (int t = 0; t < 8; ++t) {
        f16x8 v0 = *reinterpret_cast<const f16x8*>(hiA + ((size_t)(t * 4 + lk4) * NPTS + r0) * 8);
        f16x8 v1 = *reinterpret_cast<const f16x8*>(hiA + ((size_t)(t * 4 + lk4) * NPTS + r0 + 16) * 8);
#pragma unroll
        for (int e = 0; e < 8; ++e) {   // -0.5 * (-2q) = q, exact in fp16
            v0[e] = v0[e] * (_Float16)-0.5f;
            v1[e] = v1[e] * (_Float16)-0.5f;
        }
        breg0[t] = v0; breg1[t] = v1;
    }
    // augmented k-step (t=8): lk4=0 -> [1,1,0..] (picks hc+lc);
    // lk4=1 -> [hq,lq,2,0..] (picks hq+lq+4 against A's [1,1,2]); else 0.
    f16x8 b8_0 = 0, b8_1 = 0;
    {
        f16x8 raw0 = *reinterpret_cast<const f16x8*>(hiA + ((size_t)32 * NPTS + r0) * 8);
        f16x8 raw1 = *reinterpret_cast<const f16x8*>(hiA + ((size_t)32 * NPTS + r0 + 16) * 8);
        if (lk4 == 0) {
            b8_0[0] = (_Float16)1.0f; b8_0[1] = (_Float16)1.0f;
            b8_1[0] = (_Float16)1.0f; b8_1[1] = (_Float16)1.0f;
        } else if (lk4 == 1) {
            b8_0 = raw0; b8_0[2] = (_Float16)2.0f;
            b8_1 = raw1; b8_1[2] = (_Float16)2.0f;
        }
    }

    // ascending sorted top-7, packed u32
    unsigned Lp0[TOPS], Lp1[TOPS];
#pragma unroll
    for (int e = 0; e < TOPS; ++e) { Lp0[e] = 0xFFFFFFFFu; Lp1[e] = 0xFFFFFFFFu; }

#define STAGE(bufoff, tt) do {                                                \
    const int cbn_ = cand0 + (tt) * CTILE;                                    \
    _Pragma("unroll")                                                         \
    for (int i_ = 0; i_ < 4; ++i_) {                                          \
        int d_ = i_ * 8192 + tid * 16;                                        \
        int kc_ = d_ >> 10, cd_ = (d_ >> 4) & 63;                             \
        const _Float16* g_ = hiA + ((size_t)kc_ * NPTS + cbn_ + cd_) * 8;     \
        __builtin_amdgcn_global_load_lds(                                     \
            (const __attribute__((address_space(1))) void*)g_,                \
            (__attribute__((address_space(3))) void*)((char*)At + (bufoff) + d_), 16, 0, 0); \
    }                                                                         \
    if (tid < 256) {                                                          \
        int d_ = 32768 + tid * 16;                                            \
        int kc_ = d_ >> 10, cd_ = (d_ >> 4) & 63;                             \
        const _Float16* g_ = hiA + ((size_t)kc_ * NPTS + cbn_ + cd_) * 8;     \
        __builtin_amdgcn_global_load_lds(                                     \
            (const __attribute__((address_space(1))) void*)g_,                \
            (__attribute__((address_space(3))) void*)((char*)At + (bufoff) + d_), 16, 0, 0); \
    } } while (0)

    STAGE(0, rot);
    __syncthreads();

    int buf = 0;
    for (int cb = 0; cb < NCB; ++cb) {
        const int t_cur = (cb + rot) & (NCB - 1);
        if (cb + 1 < NCB) STAGE((buf ^ 1) * 36864, (cb + 1 + rot) & (NCB - 1));

        // compute: 9 k-steps x 4 cf x 2 rf = 72 MFMAs, no barriers inside
        const char* Ab = (const char*)At + buf * 36864;
        f32x4 acc0[4], acc1[4];
#pragma unroll
        for (int cf = 0; cf < 4; ++cf) {
            acc0[cf] = (f32x4){0.f, 0.f, 0.f, 0.f};
            acc1[cf] = (f32x4){0.f, 0.f, 0.f, 0.f};
        }
        __builtin_amdgcn_s_setprio(1);
#pragma unroll
        for (int t = 0; t < 9; ++t) {
            f16x8 bf0 = (t < 8) ? breg0[t] : b8_0;
            f16x8 bf1 = (t < 8) ? breg1[t] : b8_1;
#pragma unroll
            for (int cf = 0; cf < 4; ++cf) {
                f16x8 af = *reinterpret_cast<const f16x8*>(
                    Ab + (size_t)((t * 4 + lk4) * 64 + cf * 16 + lq16) * 16);
                acc0[cf] = __builtin_amdgcn_mfma_f32_16x16x32_f16(af, bf0, acc0[cf], 0, 0, 0);
                acc1[cf] = __builtin_amdgcn_mfma_f32_16x16x32_f16(af, bf1, acc1[cf], 0, 0, 0);
            }
        }
        __builtin_amdgcn_s_setprio(0);

        // epilogue: pack -> 4-CEU 2-smallest -> 2 unconditional bubbles + guarded pair
        const int cbase = cand0 + t_cur * CTILE;
#pragma unroll
        for (int cf = 0; cf < 4; ++cf) {
            const int c0 = cbase + cf * 16 + (lk4 << 2);
            {
                unsigned p0 = packsi(acc0[cf][0], c0 + 0);
                unsigned p1 = packsi(acc0[cf][1], c0 + 1);
                unsigned p2 = packsi(acc0[cf][2], c0 + 2);
                unsigned p3 = packsi(acc0[cf][3], c0 + 3);
                CEU(p0, p1); CEU(p2, p3); CEU(p0, p2); CEU(p1, p2);
                BUBBLE_U(Lp0, p0);
                BUBBLE_U(Lp0, p1);
                unsigned m23 = p2 < p3 ? p2 : p3;
                if (__any(m23 < Lp0[TOPS - 1])) { BUBBLE_U(Lp0, p2); BUBBLE_U(Lp0, p3); }
            }
            {
                unsigned p0 = packsi(acc1[cf][0], c0 + 0);
                unsigned p1 = packsi(acc1[cf][1], c0 + 1);
                unsigned p2 = packsi(acc1[cf][2], c0 + 2);
                unsigned p3 = packsi(acc1[cf][3], c0 + 3);
                CEU(p0, p1); CEU(p2, p3); CEU(p0, p2); CEU(p1, p2);
                BUBBLE_U(Lp1, p0);
                BUBBLE_U(Lp1, p1);
                unsigned m23 = p2 < p3 ? p2 : p3;
                if (__any(m23 < Lp1[TOPS - 1])) { BUBBLE_U(Lp1, p2); BUBBLE_U(Lp1, p3); }
            }
        }

        __syncthreads();   // single barrier/tile: drains prefetch + fences buf reuse
        buf ^= 1;
    }
#undef STAGE

    // ---- merge the 4 cand-partitions per row (snapshot butterfly over lk4) ----
#pragma unroll
    for (int mask = 16; mask <= 32; mask <<= 1) {
        unsigned pd[TOPS];
#pragma unroll
        for (int e = 0; e < TOPS; ++e)
            pd[e] = (unsigned)__shfl_xor((int)Lp0[e], mask, 64);
#pragma unroll
        for (int e = 0; e < TOPS; ++e) BUBBLE_U(Lp0, pd[e]);
#pragma unroll
        for (int e = 0; e < TOPS; ++e)
            pd[e] = (unsigned)__shfl_xor((int)Lp1[e], mask, 64);
#pragma unroll
        for (int e = 0; e < TOPS; ++e) BUBBLE_U(Lp1, pd[e]);
    }

    if (lk4 == 0) {   // lanes 0..15: final per-strip packed top-7 for both rows
        unsigned* dst0 = shortlist + r0 * SLW + strip * TOPS;
        unsigned* dst1 = shortlist + (r0 + 16) * SLW + strip * TOPS;
#pragma unroll
        for (int e = 0; e < TOPS; ++e) { dst0[e] = Lp0[e]; dst1[e] = Lp1[e]; }
    }
}

// K2: per row (one wave): bitonic-sort the 56 packed survivors across lanes,
// take the 16 lex-smallest, gather + exact fp32 rescore (4 lanes/cand),
// exact (dist, idx) lexicographic top-5, label match, atomic count.
__global__ __launch_bounds__(256) void rescore_kernel(const float* __restrict__ emb,
                                                      const int* __restrict__ labels,
                                                      const float* __restrict__ norms,
                                                      const unsigned* __restrict__ shortlist,
                                                      int* __restrict__ cnt) {
    __shared__ float qrow[4][DIM];
    const int tid = threadIdx.x;
    const int w = tid >> 6, l = tid & 63;
    const int q = blockIdx.x * 4 + w;

    *reinterpret_cast<float4*>(&qrow[w][l * 4]) =
        *reinterpret_cast<const float4*>(emb + (size_t)q * DIM + l * 4);

    unsigned v = 0xFFFFFFFFu;
    if (l < SLW) v = shortlist[(size_t)q * SLW + l];
    __syncthreads();

    // 64-lane bitonic sort ascending (packed u32; 8 pad lanes sort last)
#pragma unroll
    for (int k = 2; k <= 64; k <<= 1) {
#pragma unroll
        for (int j = k >> 1; j > 0; j >>= 1) {
            unsigned o = (unsigned)__shfl_xor((int)v, j, 64);
            bool keepmin = (((l & j) == 0) == ((l & k) == 0));
            unsigned mn = v < o ? v : o;
            unsigned mx = v < o ? o : v;
            v = keepmin ? mn : mx;
        }
    }

    const int cslot = l >> 2, part = l & 3;       // 16 cands x 4 lanes
    unsigned sel = (unsigned)__shfl((int)v, cslot, 64);
    int ci = (int)(sel & 0xFFFFu);

    float dv = 3.0e38f; int civ = 0x7fffffff;
    {
        const float* crow = emb + (size_t)ci * DIM + part * 64;
        const float* qr = &qrow[w][part * 64];
        float p0 = 0.f, p1 = 0.f, p2 = 0.f, p3 = 0.f;
#pragma unroll
        for (int kk = 0; kk < 16; ++kk) {
            float4 cv4 = *reinterpret_cast<const float4*>(crow + kk * 4);
            float4 qv4 = *reinterpret_cast<const float4*>(qr + kk * 4);
            p0 = fmaf(cv4.x, qv4.x, p0); p1 = fmaf(cv4.y, qv4.y, p1);
            p2 = fmaf(cv4.z, qv4.z, p2); p3 = fmaf(cv4.w, qv4.w, p3);
        }
        float p = (p0 + p1) + (p2 + p3);
        p += __shfl_xor(p, 1, 64);
        p += __shfl_xor(p, 2, 64);
        if (part == 0 && ci != q) { dv = fmaf(-2.0f, p, norms[q] + norms[ci]); civ = ci; }
    }

    const int lq = labels[q];
    bool match = false;
#pragma unroll
    for (int r = 0; r < KNN; ++r) {
        float md = dv; int mxi = civ;
#pragma unroll
        for (int mask = 1; mask <= 32; mask <<= 1) {
            float pd = __shfl_xor(md, mask, 64);
            int   pi = __shfl_xor(mxi, mask, 64);
            if (pd < md || (pd == md && pi < mxi)) { md = pd; mxi = pi; }
        }
        if (civ == mxi) dv = 3.0e38f;   // owner retires its candidate
        match = match || (labels[mxi] == lq);
    }
    if (l == 0) atomicAdd(cnt, match ? 1 : 0);
}

// K3: scalar output = count / N (power-of-two divide, exact)
__global__ void finalize_kernel(const int* __restrict__ cnt, float* __restrict__ out) {
    if (threadIdx.x == 0) out[0] = (float)(*cnt) * (1.0f / (float)NPTS);
}

extern "C" void kernel_launch(void* const* d_in, const int* in_sizes, int n_in,
                              void* d_out, int out_size, void* d_ws, size_t ws_size,
                              hipStream_t stream) {
    (void)in_sizes; (void)n_in; (void)out_size; (void)ws_size;
    const float* emb    = (const float*)d_in[0];
    const int*   labels = (const int*)d_in[1];
    float*       out    = (float*)d_out;

    char* ws = (char*)d_ws;
    int*       cnt       = (int*)(ws + WS_CNT);
    float*     norms     = (float*)(ws + WS_NORMS);
    _Float16*  hiA       = (_Float16*)(ws + WS_HIA);
    unsigned*  shortlist = (unsigned*)(ws + WS_SL);

    prep_kernel<<<NPTS / 4, 256, 0, stream>>>(emb, norms, hiA, cnt);
    filter_kernel<<<(NPTS / RPB) * STRIPS, 512, 0, stream>>>(hiA, shortlist);
    rescore_kernel<<<NPTS / 4, 256, 0, stream>>>(emb, labels, norms, shortlist, cnt);
    finalize_kernel<<<1, 64, 0, stream>>>(cnt, out);
}

// Round 11
// 417.068 us; speedup vs baseline: 3.4273x; 1.0030x over previous
//
#include <hip/hip_runtime.h>

#define NPTS 16384
#define DIM 256
#define NKC 36                 // augmented kchunks: 32 data + [hc,lc] + [1,1,2] + 2 pad
#define KNN 5
#define RPB 256                // rows per block = 8 waves x 32
#define CTILE 64               // candidates per tile
#define STRIPS 8
#define STRIP (NPTS / STRIPS)  // 2048
#define NCB (STRIP / CTILE)    // 32
#define TOPS 7                 // per-strip shortlist depth (self + 5 + 1 spare)
#define SLW (STRIPS * TOPS)    // 56 shortlist slots per row
#define SEL 8                  // candidates rescored exactly per row

typedef _Float16 f16x8 __attribute__((ext_vector_type(8)));
typedef float    f32x4 __attribute__((ext_vector_type(4)));

// workspace byte offsets
#define WS_CNT   0
#define WS_NORMS 4096                          // float [NPTS]
#define WS_HIA   (WS_NORMS + NPTS * 4)         // _Float16 [NKC][NPTS][8] k-major
#define WS_SL    (WS_HIA + NPTS * NKC * 16)    // unsigned [NPTS][SLW]

// pack positive fp16 score + 14-bit idx into one sortable u32
__device__ __forceinline__ unsigned packsi(float s, int idx) {
    union { _Float16 h; unsigned short u; } cv;
    cv.h = (_Float16)s;                       // RNE, score > 0 by construction
    return ((unsigned)cv.u << 16) | (unsigned)idx;
}

// compare-exchange (min/max) on packed u32 — 2 VALU ops, idx travels free
#define CEU(a, b) do {                                                        \
    unsigned mn_ = (a) < (b) ? (a) : (b);                                     \
    unsigned mx_ = (a) < (b) ? (b) : (a);                                     \
    (a) = mn_; (b) = mx_;                                                     \
} while (0)

// bubble x into ascending sorted TOPS-list of packed u32 (no-op if too big)
#define BUBBLE_U(Lp, x) do {                                                  \
    unsigned c_ = (x);                                                        \
    _Pragma("unroll")                                                         \
    for (int e_ = 0; e_ < TOPS; ++e_) {                                       \
        unsigned mn_ = c_ < Lp[e_] ? c_ : Lp[e_];                             \
        unsigned mx_ = c_ < Lp[e_] ? Lp[e_] : c_;                             \
        Lp[e_] = mn_; c_ = mx_;                                               \
    } } while (0)

// K0: k-major augmented fp16 buffer hiA[kc][row][8]:
// kc 0..31 = -2*fp16(row), kc32 = [h,l,0..] (h+l ~= ||row||^2),
// kc33 = [1,1,2,0..] (constant), kc34/35 = 0. Plus fp32 norms, counter=0.
__global__ __launch_bounds__(256) void prep_kernel(const float* __restrict__ emb,
                                                   float* __restrict__ norms,
                                                   _Float16* __restrict__ hiA,
                                                   int* __restrict__ cnt) {
    if (blockIdx.x == 0 && threadIdx.x == 0) *cnt = 0;
    const int row = blockIdx.x * 4 + (threadIdx.x >> 6);
    const int l   = threadIdx.x & 63;
    float4 v = *reinterpret_cast<const float4*>(emb + (size_t)row * DIM + l * 4);
    union { _Float16 h[4]; short4 s; } u;
    u.h[0] = (_Float16)v.x * (_Float16)-2.0f;
    u.h[1] = (_Float16)v.y * (_Float16)-2.0f;
    u.h[2] = (_Float16)v.z * (_Float16)-2.0f;
    u.h[3] = (_Float16)v.w * (_Float16)-2.0f;
    *reinterpret_cast<short4*>(hiA + ((size_t)(l >> 1) * NPTS + row) * 8 + (l & 1) * 4) = u.s;

    float s = v.x * v.x + v.y * v.y + v.z * v.z + v.w * v.w;
#pragma unroll
    for (int off = 32; off > 0; off >>= 1) s += __shfl_down(s, off, 64);
    float tot = __shfl(s, 0, 64);
    if (l == 0) norms[row] = tot;
    if (l < 4) {   // chunks 32..35
        union { _Float16 h[4]; short4 s; } z0, z1;
        z0.h[0] = (_Float16)0.f; z0.h[1] = (_Float16)0.f;
        z0.h[2] = (_Float16)0.f; z0.h[3] = (_Float16)0.f;
        z1 = z0;
        if (l == 0) {
            _Float16 hh = (_Float16)tot;
            _Float16 ll = (_Float16)(tot - (float)hh);
            z0.h[0] = hh; z0.h[1] = ll;
        }
        if (l == 1) {   // A-side of the +||q||^2+4 fold
            z0.h[0] = (_Float16)1.0f; z0.h[1] = (_Float16)1.0f; z0.h[2] = (_Float16)2.0f;
        }
        _Float16* dst = hiA + ((size_t)(32 + l) * NPTS + row) * 8;
        *reinterpret_cast<short4*>(dst)     = z0.s;
        *reinterpret_cast<short4*>(dst + 4) = z1.s;
    }
}

// K1: MFMA filter (r10 geometry + counted-vmcnt pipeline, no drain-to-0 in loop).
__global__ __launch_bounds__(512, 4) void filter_kernel(const _Float16* __restrict__ hiA,
                                                        unsigned* __restrict__ shortlist) {
    __shared__ _Float16 At[2 * NKC * CTILE * 8];   // 73728 B
    const int tid  = threadIdx.x;
    const int w    = tid >> 6;        // wave 0..7
    const int l    = tid & 63;
    const int lq16 = l & 15;          // D col = query-row-in-16
    const int lk4  = l >> 4;          // k-quarter / cand sub-group
    const int panel = blockIdx.x >> 3;
    const int strip = blockIdx.x & 7; // native XCD slot -> strip slice L2-resident
    const int qbase = panel * RPB;
    const int cand0 = strip * STRIP;
    const int rot   = panel & (NCB - 1);   // phase-decorrelated tile start

    // ---- B fragments resident: 2 rf x 8 t (kc = t*4+lk4), coalesced loads ----
    const size_t r0 = (size_t)qbase + w * 32 + lq16;
    f16x8 breg0[8], breg1[8];
#pragma unroll
    for (int t = 0; t < 8; ++t) {
        f16x8 v0 = *reinterpret_cast<const f16x8*>(hiA + ((size_t)(t * 4 + lk4) * NPTS + r0) * 8);
        f16x8 v1 = *reinterpret_cast<const f16x8*>(hiA + ((size_t)(t * 4 + lk4) * NPTS + r0 + 16) * 8);
#pragma unroll
        for (int e = 0; e < 8; ++e) {   // -0.5 * (-2q) = q, exact in fp16
            v0[e] = v0[e] * (_Float16)-0.5f;
            v1[e] = v1[e] * (_Float16)-0.5f;
        }
        breg0[t] = v0; breg1[t] = v1;
    }
    // augmented k-step (t=8): lk4=0 -> [1,1,0..] (picks hc+lc);
    // lk4=1 -> [hq,lq,2,0..] (picks hq+lq+4 against A's [1,1,2]); else 0.
    f16x8 b8_0 = 0, b8_1 = 0;
    {
        f16x8 raw0 = *reinterpret_cast<const f16x8*>(hiA + ((size_t)32 * NPTS + r0) * 8);
        f16x8 raw1 = *reinterpret_cast<const f16x8*>(hiA + ((size_t)32 * NPTS + r0 + 16) * 8);
        if (lk4 == 0) {
            b8_0[0] = (_Float16)1.0f; b8_0[1] = (_Float16)1.0f;
            b8_1[0] = (_Float16)1.0f; b8_1[1] = (_Float16)1.0f;
        } else if (lk4 == 1) {
            b8_0 = raw0; b8_0[2] = (_Float16)2.0f;
            b8_1 = raw1; b8_1[2] = (_Float16)2.0f;
        }
    }

    // ascending sorted top-7, packed u32
    unsigned Lp0[TOPS], Lp1[TOPS];
#pragma unroll
    for (int e = 0; e < TOPS; ++e) { Lp0[e] = 0xFFFFFFFFu; Lp1[e] = 0xFFFFFFFFu; }

    // waves 0..3 issue 9 loads per STAGE; waves 4..7 issue 8 (wave-uniform split)
#define STAGE(bufoff, tt) do {                                                \
    const int cbn_ = cand0 + (tt) * CTILE;                                    \
    _Pragma("unroll")                                                         \
    for (int i_ = 0; i_ < 4; ++i_) {                                          \
        int d_ = i_ * 8192 + tid * 16;                                        \
        int kc_ = d_ >> 10, cd_ = (d_ >> 4) & 63;                             \
        const _Float16* g_ = hiA + ((size_t)kc_ * NPTS + cbn_ + cd_) * 8;     \
        __builtin_amdgcn_global_load_lds(                                     \
            (const __attribute__((address_space(1))) void*)g_,                \
            (__attribute__((address_space(3))) void*)((char*)At + (bufoff) + d_), 16, 0, 0); \
    }                                                                         \
    if (tid < 256) {                                                          \
        int d_ = 32768 + tid * 16;                                            \
        int kc_ = d_ >> 10, cd_ = (d_ >> 4) & 63;                             \
        const _Float16* g_ = hiA + ((size_t)kc_ * NPTS + cbn_ + cd_) * 8;     \
        __builtin_amdgcn_global_load_lds(                                     \
            (const __attribute__((address_space(1))) void*)g_,                \
            (__attribute__((address_space(3))) void*)((char*)At + (bufoff) + d_), 16, 0, 0); \
    } } while (0)

    STAGE(0, rot);

    int buf = 0;
    for (int cb = 0; cb < NCB; ++cb) {
        const int t_cur = (cb + rot) & (NCB - 1);
        // issue next-tile loads, then wait ONLY for the current tile's loads
        if (cb + 1 < NCB) {
            STAGE((buf ^ 1) * 36864, (cb + 1 + rot) & (NCB - 1));
            if (w < 4) { asm volatile("s_waitcnt vmcnt(9)" ::: "memory"); }
            else       { asm volatile("s_waitcnt vmcnt(8)" ::: "memory"); }
        } else {
            asm volatile("s_waitcnt vmcnt(0)" ::: "memory");
        }
        __builtin_amdgcn_sched_barrier(0);
        __builtin_amdgcn_s_barrier();      // all waves: current buf fully landed
        __builtin_amdgcn_sched_barrier(0);

        // compute: 9 k-steps x 4 cf x 2 rf = 72 MFMAs, no barriers inside
        const char* Ab = (const char*)At + buf * 36864;
        f32x4 acc0[4], acc1[4];
#pragma unroll
        for (int cf = 0; cf < 4; ++cf) {
            acc0[cf] = (f32x4){0.f, 0.f, 0.f, 0.f};
            acc1[cf] = (f32x4){0.f, 0.f, 0.f, 0.f};
        }
        __builtin_amdgcn_s_setprio(1);
#pragma unroll
        for (int t = 0; t < 9; ++t) {
            f16x8 bf0 = (t < 8) ? breg0[t] : b8_0;
            f16x8 bf1 = (t < 8) ? breg1[t] : b8_1;
#pragma unroll
            for (int cf = 0; cf < 4; ++cf) {
                f16x8 af = *reinterpret_cast<const f16x8*>(
                    Ab + (size_t)((t * 4 + lk4) * 64 + cf * 16 + lq16) * 16);
                acc0[cf] = __builtin_amdgcn_mfma_f32_16x16x32_f16(af, bf0, acc0[cf], 0, 0, 0);
                acc1[cf] = __builtin_amdgcn_mfma_f32_16x16x32_f16(af, bf1, acc1[cf], 0, 0, 0);
            }
        }
        __builtin_amdgcn_s_setprio(0);

        // epilogue: pack -> 4-CEU 2-smallest -> 2 unconditional bubbles + guarded pair
        const int cbase = cand0 + t_cur * CTILE;
#pragma unroll
        for (int cf = 0; cf < 4; ++cf) {
            const int c0 = cbase + cf * 16 + (lk4 << 2);
            {
                unsigned p0 = packsi(acc0[cf][0], c0 + 0);
                unsigned p1 = packsi(acc0[cf][1], c0 + 1);
                unsigned p2 = packsi(acc0[cf][2], c0 + 2);
                unsigned p3 = packsi(acc0[cf][3], c0 + 3);
                CEU(p0, p1); CEU(p2, p3); CEU(p0, p2); CEU(p1, p2);
                BUBBLE_U(Lp0, p0);
                BUBBLE_U(Lp0, p1);
                unsigned m23 = p2 < p3 ? p2 : p3;
                if (__any(m23 < Lp0[TOPS - 1])) { BUBBLE_U(Lp0, p2); BUBBLE_U(Lp0, p3); }
            }
            {
                unsigned p0 = packsi(acc1[cf][0], c0 + 0);
                unsigned p1 = packsi(acc1[cf][1], c0 + 1);
                unsigned p2 = packsi(acc1[cf][2], c0 + 2);
                unsigned p3 = packsi(acc1[cf][3], c0 + 3);
                CEU(p0, p1); CEU(p2, p3); CEU(p0, p2); CEU(p1, p2);
                BUBBLE_U(Lp1, p0);
                BUBBLE_U(Lp1, p1);
                unsigned m23 = p2 < p3 ? p2 : p3;
                if (__any(m23 < Lp1[TOPS - 1])) { BUBBLE_U(Lp1, p2); BUBBLE_U(Lp1, p3); }
            }
        }

        // fence buf reuse: LDS reads complete, then barrier (NO vmcnt drain)
        asm volatile("s_waitcnt lgkmcnt(0)" ::: "memory");
        __builtin_amdgcn_sched_barrier(0);
        __builtin_amdgcn_s_barrier();
        __builtin_amdgcn_sched_barrier(0);
        buf ^= 1;
    }
#undef STAGE

    // ---- merge the 4 cand-partitions per row (snapshot butterfly over lk4) ----
#pragma unroll
    for (int mask = 16; mask <= 32; mask <<= 1) {
        unsigned pd[TOPS];
#pragma unroll
        for (int e = 0; e < TOPS; ++e)
            pd[e] = (unsigned)__shfl_xor((int)Lp0[e], mask, 64);
#pragma unroll
        for (int e = 0; e < TOPS; ++e) BUBBLE_U(Lp0, pd[e]);
#pragma unroll
        for (int e = 0; e < TOPS; ++e)
            pd[e] = (unsigned)__shfl_xor((int)Lp1[e], mask, 64);
#pragma unroll
        for (int e = 0; e < TOPS; ++e) BUBBLE_U(Lp1, pd[e]);
    }

    if (lk4 == 0) {   // lanes 0..15: final per-strip packed top-7 for both rows
        unsigned* dst0 = shortlist + r0 * SLW + strip * TOPS;
        unsigned* dst1 = shortlist + (r0 + 16) * SLW + strip * TOPS;
#pragma unroll
        for (int e = 0; e < TOPS; ++e) { dst0[e] = Lp0[e]; dst1[e] = Lp1[e]; }
    }
}

// K2: per row (one wave): bitonic-sort the 56 packed survivors across lanes,
// take the 8 lex-smallest, gather + exact fp32 rescore (8 lanes/cand),
// exact (dist, idx) lexicographic top-5, label match, atomic count.
__global__ __launch_bounds__(256) void rescore_kernel(const float* __restrict__ emb,
                                                      const int* __restrict__ labels,
                                                      const float* __restrict__ norms,
                                                      const unsigned* __restrict__ shortlist,
                                                      int* __restrict__ cnt) {
    __shared__ float qrow[4][DIM];
    const int tid = threadIdx.x;
    const int w = tid >> 6, l = tid & 63;
    const int q = blockIdx.x * 4 + w;

    *reinterpret_cast<float4*>(&qrow[w][l * 4]) =
        *reinterpret_cast<const float4*>(emb + (size_t)q * DIM + l * 4);

    unsigned v = 0xFFFFFFFFu;
    if (l < SLW) v = shortlist[(size_t)q * SLW + l];
    __syncthreads();

    // 64-lane bitonic sort ascending (packed u32; 8 pad lanes sort last)
#pragma unroll
    for (int k = 2; k <= 64; k <<= 1) {
#pragma unroll
        for (int j = k >> 1; j > 0; j >>= 1) {
            unsigned o = (unsigned)__shfl_xor((int)v, j, 64);
            bool keepmin = (((l & j) == 0) == ((l & k) == 0));
            unsigned mn = v < o ? v : o;
            unsigned mx = v < o ? o : v;
            v = keepmin ? mn : mx;
        }
    }

    const int cslot = l >> 3, part = l & 7;       // 8 cands x 8 lanes
    unsigned sel = (unsigned)__shfl((int)v, cslot, 64);
    int ci = (int)(sel & 0xFFFFu);

    float dv = 3.0e38f; int civ = 0x7fffffff;
    {
        const float* crow = emb + (size_t)ci * DIM + part * 32;   // 32 dims/lane
        const float* qr = &qrow[w][part * 32];
        float p0 = 0.f, p1 = 0.f, p2 = 0.f, p3 = 0.f;
#pragma unroll
        for (int kk = 0; kk < 8; ++kk) {
            float4 cv4 = *reinterpret_cast<const float4*>(crow + kk * 4);
            float4 qv4 = *reinterpret_cast<const float4*>(qr + kk * 4);
            p0 = fmaf(cv4.x, qv4.x, p0); p1 = fmaf(cv4.y, qv4.y, p1);
            p2 = fmaf(cv4.z, qv4.z, p2); p3 = fmaf(cv4.w, qv4.w, p3);
        }
        float p = (p0 + p1) + (p2 + p3);
        p += __shfl_xor(p, 1, 64);
        p += __shfl_xor(p, 2, 64);
        p += __shfl_xor(p, 4, 64);
        if (part == 0 && ci != q) { dv = fmaf(-2.0f, p, norms[q] + norms[ci]); civ = ci; }
    }

    // relocate the 8 (dist,idx) to every 8-lane coset: lane reads lane (l&7)*8
    float dv2 = __shfl(dv, (l & 7) * 8, 64);
    int  civ2 = __shfl(civ, (l & 7) * 8, 64);

    const int lq = labels[q];
    bool match = false;
#pragma unroll
    for (int r = 0; r < KNN; ++r) {
        float md = dv2; int mxi = civ2;
#pragma unroll
        for (int mask = 1; mask <= 4; mask <<= 1) {
            float pd = __shfl_xor(md, mask, 64);
            int   pi = __shfl_xor(mxi, mask, 64);
            if (pd < md || (pd == md && pi < mxi)) { md = pd; mxi = pi; }
        }
        if (civ2 == mxi) dv2 = 3.0e38f;   // owner copy retires in every coset
        match = match || (labels[mxi] == lq);
    }
    if (l == 0) atomicAdd(cnt, match ? 1 : 0);
}

// K3: scalar output = count / N (power-of-two divide, exact)
__global__ void finalize_kernel(const int* __restrict__ cnt, float* __restrict__ out) {
    if (threadIdx.x == 0) out[0] = (float)(*cnt) * (1.0f / (float)NPTS);
}

extern "C" void kernel_launch(void* const* d_in, const int* in_sizes, int n_in,
                              void* d_out, int out_size, void* d_ws, size_t ws_size,
                              hipStream_t stream) {
    (void)in_sizes; (void)n_in; (void)out_size; (void)ws_size;
    const float* emb    = (const float*)d_in[0];
    const int*   labels = (const int*)d_in[1];
    float*       out    = (float*)d_out;

    char* ws = (char*)d_ws;
    int*       cnt       = (int*)(ws + WS_CNT);
    float*     norms     = (float*)(ws + WS_NORMS);
    _Float16*  hiA       = (_Float16*)(ws + WS_HIA);
    unsigned*  shortlist = (unsigned*)(ws + WS_SL);

    prep_kernel<<<NPTS / 4, 256, 0, stream>>>(emb, norms, hiA, cnt);
    filter_kernel<<<(NPTS / RPB) * STRIPS, 512, 0, stream>>>(hiA, shortlist);
    rescore_kernel<<<NPTS / 4, 256, 0, stream>>>(emb, labels, norms, shortlist, cnt);
    finalize_kernel<<<1, 64, 0, stream>>>(cnt, out);
}

// Round 12
// 377.567 us; speedup vs baseline: 3.7859x; 1.1046x over previous
//
#include <hip/hip_runtime.h>

#define NPTS 16384
#define DIM 256
#define NKC 36                 // augmented kchunks: 32 data + [hc,lc] + [1,1,2] + 2 pad
#define KNN 5
#define RPB 256                // rows per block = 8 waves x 32
#define CTILE 64               // candidates per tile
#define STRIPS 8
#define STRIP (NPTS / STRIPS)  // 2048
#define NCB (STRIP / CTILE)    // 32
#define TOPS 7                 // per-strip shortlist depth (self + 5 + 1 spare)
#define SLW (STRIPS * TOPS)    // 56 shortlist slots per row
#define SEL 8                  // candidates rescored exactly per row

typedef _Float16 f16x8 __attribute__((ext_vector_type(8)));
typedef float    f32x4 __attribute__((ext_vector_type(4)));

// workspace byte offsets
#define WS_CNT   0
#define WS_NORMS 4096                          // float [NPTS]
#define WS_HIA   (WS_NORMS + NPTS * 4)         // _Float16 [NKC][NPTS][8] k-major
#define WS_SL    (WS_HIA + NPTS * NKC * 16)    // unsigned [NPTS][SLW]

// pack positive fp16 score + 14-bit idx into one sortable u32
__device__ __forceinline__ unsigned packsi(float s, int idx) {
    union { _Float16 h; unsigned short u; } cv;
    cv.h = (_Float16)s;                       // RNE, score > 0 by construction
    return ((unsigned)cv.u << 16) | (unsigned)idx;
}

// compare-exchange (min/max) on packed u32 — 2 VALU ops, idx travels free
#define CEU(a, b) do {                                                        \
    unsigned mn_ = (a) < (b) ? (a) : (b);                                     \
    unsigned mx_ = (a) < (b) ? (b) : (a);                                     \
    (a) = mn_; (b) = mx_;                                                     \
} while (0)

// bubble x into ascending sorted TOPS-list of packed u32 (no-op if too big)
#define BUBBLE_U(Lp, x) do {                                                  \
    unsigned c_ = (x);                                                        \
    _Pragma("unroll")                                                         \
    for (int e_ = 0; e_ < TOPS; ++e_) {                                       \
        unsigned mn_ = c_ < Lp[e_] ? c_ : Lp[e_];                             \
        unsigned mx_ = c_ < Lp[e_] ? Lp[e_] : c_;                             \
        Lp[e_] = mn_; c_ = mx_;                                               \
    } } while (0)

// K0: k-major augmented fp16 buffer hiA[kc][row][8]:
// kc 0..31 = -2*fp16(row), kc32 = [h,l,0..] (h+l ~= ||row||^2),
// kc33 = [1,1,2,0..] (constant), kc34/35 = 0. Plus fp32 norms, counter=0.
__global__ __launch_bounds__(256) void prep_kernel(const float* __restrict__ emb,
                                                   float* __restrict__ norms,
                                                   _Float16* __restrict__ hiA,
                                                   int* __restrict__ cnt) {
    if (blockIdx.x == 0 && threadIdx.x == 0) *cnt = 0;
    const int row = blockIdx.x * 4 + (threadIdx.x >> 6);
    const int l   = threadIdx.x & 63;
    float4 v = *reinterpret_cast<const float4*>(emb + (size_t)row * DIM + l * 4);
    union { _Float16 h[4]; short4 s; } u;
    u.h[0] = (_Float16)v.x * (_Float16)-2.0f;
    u.h[1] = (_Float16)v.y * (_Float16)-2.0f;
    u.h[2] = (_Float16)v.z * (_Float16)-2.0f;
    u.h[3] = (_Float16)v.w * (_Float16)-2.0f;
    *reinterpret_cast<short4*>(hiA + ((size_t)(l >> 1) * NPTS + row) * 8 + (l & 1) * 4) = u.s;

    float s = v.x * v.x + v.y * v.y + v.z * v.z + v.w * v.w;
#pragma unroll
    for (int off = 32; off > 0; off >>= 1) s += __shfl_down(s, off, 64);
    float tot = __shfl(s, 0, 64);
    if (l == 0) norms[row] = tot;
    if (l < 4) {   // chunks 32..35
        union { _Float16 h[4]; short4 s; } z0, z1;
        z0.h[0] = (_Float16)0.f; z0.h[1] = (_Float16)0.f;
        z0.h[2] = (_Float16)0.f; z0.h[3] = (_Float16)0.f;
        z1 = z0;
        if (l == 0) {
            _Float16 hh = (_Float16)tot;
            _Float16 ll = (_Float16)(tot - (float)hh);
            z0.h[0] = hh; z0.h[1] = ll;
        }
        if (l == 1) {   // A-side of the +||q||^2+4 fold
            z0.h[0] = (_Float16)1.0f; z0.h[1] = (_Float16)1.0f; z0.h[2] = (_Float16)2.0f;
        }
        _Float16* dst = hiA + ((size_t)(32 + l) * NPTS + row) * 8;
        *reinterpret_cast<short4*>(dst)     = z0.s;
        *reinterpret_cast<short4*>(dst + 4) = z1.s;
    }
}

// K1: MFMA filter — cf-major pipelined: MFMA burst of column cf overlaps the
// VALU epilogue of column cf-1 (per-acc t-order unchanged -> identical bits).
__global__ __launch_bounds__(512, 4) void filter_kernel(const _Float16* __restrict__ hiA,
                                                        unsigned* __restrict__ shortlist) {
    __shared__ _Float16 At[2 * NKC * CTILE * 8];   // 73728 B
    const int tid  = threadIdx.x;
    const int w    = tid >> 6;        // wave 0..7
    const int l    = tid & 63;
    const int lq16 = l & 15;          // D col = query-row-in-16
    const int lk4  = l >> 4;          // k-quarter / cand sub-group
    const int panel = blockIdx.x >> 3;
    const int strip = blockIdx.x & 7; // native XCD slot -> strip slice L2-resident
    const int qbase = panel * RPB;
    const int cand0 = strip * STRIP;
    const int rot   = panel & (NCB - 1);   // phase-decorrelated tile start

    // ---- B fragments resident: 2 rf x 8 t (kc = t*4+lk4), coalesced loads ----
    const size_t r0 = (size_t)qbase + w * 32 + lq16;
    f16x8 breg0[8], breg1[8];
#pragma unroll
    for (int t = 0; t < 8; ++t) {
        f16x8 v0 = *reinterpret_cast<const f16x8*>(hiA + ((size_t)(t * 4 + lk4) * NPTS + r0) * 8);
        f16x8 v1 = *reinterpret_cast<const f16x8*>(hiA + ((size_t)(t * 4 + lk4) * NPTS + r0 + 16) * 8);
#pragma unroll
        for (int e = 0; e < 8; ++e) {   // -0.5 * (-2q) = q, exact in fp16
            v0[e] = v0[e] * (_Float16)-0.5f;
            v1[e] = v1[e] * (_Float16)-0.5f;
        }
        breg0[t] = v0; breg1[t] = v1;
    }
    // augmented k-step (t=8): lk4=0 -> [1,1,0..] (picks hc+lc);
    // lk4=1 -> [hq,lq,2,0..] (picks hq+lq+4 against A's [1,1,2]); else 0.
    f16x8 b8_0 = 0, b8_1 = 0;
    {
        f16x8 raw0 = *reinterpret_cast<const f16x8*>(hiA + ((size_t)32 * NPTS + r0) * 8);
        f16x8 raw1 = *reinterpret_cast<const f16x8*>(hiA + ((size_t)32 * NPTS + r0 + 16) * 8);
        if (lk4 == 0) {
            b8_0[0] = (_Float16)1.0f; b8_0[1] = (_Float16)1.0f;
            b8_1[0] = (_Float16)1.0f; b8_1[1] = (_Float16)1.0f;
        } else if (lk4 == 1) {
            b8_0 = raw0; b8_0[2] = (_Float16)2.0f;
            b8_1 = raw1; b8_1[2] = (_Float16)2.0f;
        }
    }

    // ascending sorted top-7, packed u32
    unsigned Lp0[TOPS], Lp1[TOPS];
#pragma unroll
    for (int e = 0; e < TOPS; ++e) { Lp0[e] = 0xFFFFFFFFu; Lp1[e] = 0xFFFFFFFFu; }

    // waves 0..3 issue 9 loads per STAGE; waves 4..7 issue 8 (wave-uniform split)
#define STAGE(bufoff, tt) do {                                                \
    const int cbn_ = cand0 + (tt) * CTILE;                                    \
    _Pragma("unroll")                                                         \
    for (int i_ = 0; i_ < 4; ++i_) {                                          \
        int d_ = i_ * 8192 + tid * 16;                                        \
        int kc_ = d_ >> 10, cd_ = (d_ >> 4) & 63;                             \
        const _Float16* g_ = hiA + ((size_t)kc_ * NPTS + cbn_ + cd_) * 8;     \
        __builtin_amdgcn_global_load_lds(                                     \
            (const __attribute__((address_space(1))) void*)g_,                \
            (__attribute__((address_space(3))) void*)((char*)At + (bufoff) + d_), 16, 0, 0); \
    }                                                                         \
    if (tid < 256) {                                                          \
        int d_ = 32768 + tid * 16;                                            \
        int kc_ = d_ >> 10, cd_ = (d_ >> 4) & 63;                             \
        const _Float16* g_ = hiA + ((size_t)kc_ * NPTS + cbn_ + cd_) * 8;     \
        __builtin_amdgcn_global_load_lds(                                     \
            (const __attribute__((address_space(1))) void*)g_,                \
            (__attribute__((address_space(3))) void*)((char*)At + (bufoff) + d_), 16, 0, 0); \
    } } while (0)

// MFMA burst for candidate column cf: 9 k-steps x 2 rf (t ascending per acc)
#define MFMA_CF(cf) do {                                                      \
    _Pragma("unroll")                                                         \
    for (int t_ = 0; t_ < 9; ++t_) {                                          \
        f16x8 bf0_ = (t_ < 8) ? breg0[t_] : b8_0;                             \
        f16x8 bf1_ = (t_ < 8) ? breg1[t_] : b8_1;                             \
        f16x8 af_ = *reinterpret_cast<const f16x8*>(                          \
            Ab + (size_t)((t_ * 4 + lk4) * 64 + (cf) * 16 + lq16) * 16);      \
        acc0[cf] = __builtin_amdgcn_mfma_f32_16x16x32_f16(af_, bf0_, acc0[cf], 0, 0, 0); \
        acc1[cf] = __builtin_amdgcn_mfma_f32_16x16x32_f16(af_, bf1_, acc1[cf], 0, 0, 0); \
    } } while (0)

// epilogue for column cf: pack -> 4-CEU 2-smallest -> bubbles + guarded pair
#define EPI_CF(cf) do {                                                       \
    const int c0_ = cbase + (cf) * 16 + (lk4 << 2);                           \
    {                                                                         \
        unsigned p0 = packsi(acc0[cf][0], c0_ + 0);                           \
        unsigned p1 = packsi(acc0[cf][1], c0_ + 1);                           \
        unsigned p2 = packsi(acc0[cf][2], c0_ + 2);                           \
        unsigned p3 = packsi(acc0[cf][3], c0_ + 3);                           \
        CEU(p0, p1); CEU(p2, p3); CEU(p0, p2); CEU(p1, p2);                   \
        BUBBLE_U(Lp0, p0);                                                    \
        BUBBLE_U(Lp0, p1);                                                    \
        unsigned m23 = p2 < p3 ? p2 : p3;                                     \
        if (__any(m23 < Lp0[TOPS - 1])) { BUBBLE_U(Lp0, p2); BUBBLE_U(Lp0, p3); } \
    }                                                                         \
    {                                                                         \
        unsigned p0 = packsi(acc1[cf][0], c0_ + 0);                           \
        unsigned p1 = packsi(acc1[cf][1], c0_ + 1);                           \
        unsigned p2 = packsi(acc1[cf][2], c0_ + 2);                           \
        unsigned p3 = packsi(acc1[cf][3], c0_ + 3);                           \
        CEU(p0, p1); CEU(p2, p3); CEU(p0, p2); CEU(p1, p2);                   \
        BUBBLE_U(Lp1, p0);                                                    \
        BUBBLE_U(Lp1, p1);                                                    \
        unsigned m23 = p2 < p3 ? p2 : p3;                                     \
        if (__any(m23 < Lp1[TOPS - 1])) { BUBBLE_U(Lp1, p2); BUBBLE_U(Lp1, p3); } \
    } } while (0)

    STAGE(0, rot);

    int buf = 0;
    for (int cb = 0; cb < NCB; ++cb) {
        const int t_cur = (cb + rot) & (NCB - 1);
        // issue next-tile loads, then wait ONLY for the current tile's loads
        if (cb + 1 < NCB) {
            STAGE((buf ^ 1) * 36864, (cb + 1 + rot) & (NCB - 1));
            if (w < 4) { asm volatile("s_waitcnt vmcnt(9)" ::: "memory"); }
            else       { asm volatile("s_waitcnt vmcnt(8)" ::: "memory"); }
        } else {
            asm volatile("s_waitcnt vmcnt(0)" ::: "memory");
        }
        __builtin_amdgcn_sched_barrier(0);
        __builtin_amdgcn_s_barrier();      // all waves: current buf fully landed
        __builtin_amdgcn_sched_barrier(0);

        const char* Ab = (const char*)At + buf * 36864;
        const int cbase = cand0 + t_cur * CTILE;
        f32x4 acc0[4], acc1[4];
#pragma unroll
        for (int cf = 0; cf < 4; ++cf) {
            acc0[cf] = (f32x4){0.f, 0.f, 0.f, 0.f};
            acc1[cf] = (f32x4){0.f, 0.f, 0.f, 0.f};
        }

        // cf-major pipeline: MFMA burst cf overlaps epilogue of cf-1
        __builtin_amdgcn_s_setprio(1);
        MFMA_CF(0);
        MFMA_CF(1); EPI_CF(0);
        MFMA_CF(2); EPI_CF(1);
        MFMA_CF(3); EPI_CF(2);
        __builtin_amdgcn_s_setprio(0);
        EPI_CF(3);

        // fence buf reuse: LDS reads complete, then barrier (NO vmcnt drain)
        asm volatile("s_waitcnt lgkmcnt(0)" ::: "memory");
        __builtin_amdgcn_sched_barrier(0);
        __builtin_amdgcn_s_barrier();
        __builtin_amdgcn_sched_barrier(0);
        buf ^= 1;
    }
#undef STAGE
#undef MFMA_CF
#undef EPI_CF

    // ---- merge the 4 cand-partitions per row (snapshot butterfly over lk4) ----
#pragma unroll
    for (int mask = 16; mask <= 32; mask <<= 1) {
        unsigned pd[TOPS];
#pragma unroll
        for (int e = 0; e < TOPS; ++e)
            pd[e] = (unsigned)__shfl_xor((int)Lp0[e], mask, 64);
#pragma unroll
        for (int e = 0; e < TOPS; ++e) BUBBLE_U(Lp0, pd[e]);
#pragma unroll
        for (int e = 0; e < TOPS; ++e)
            pd[e] = (unsigned)__shfl_xor((int)Lp1[e], mask, 64);
#pragma unroll
        for (int e = 0; e < TOPS; ++e) BUBBLE_U(Lp1, pd[e]);
    }

    if (lk4 == 0) {   // lanes 0..15: final per-strip packed top-7 for both rows
        unsigned* dst0 = shortlist + r0 * SLW + strip * TOPS;
        unsigned* dst1 = shortlist + (r0 + 16) * SLW + strip * TOPS;
#pragma unroll
        for (int e = 0; e < TOPS; ++e) { dst0[e] = Lp0[e]; dst1[e] = Lp1[e]; }
    }
}

// K2: per row (one wave): bitonic-sort the 56 packed survivors across lanes,
// take the 8 lex-smallest, gather + exact fp32 rescore (8 lanes/cand),
// exact (dist, idx) lexicographic top-5, label match, atomic count.
__global__ __launch_bounds__(256) void rescore_kernel(const float* __restrict__ emb,
                                                      const int* __restrict__ labels,
                                                      const float* __restrict__ norms,
                                                      const unsigned* __restrict__ shortlist,
                                                      int* __restrict__ cnt) {
    __shared__ float qrow[4][DIM];
    const int tid = threadIdx.x;
    const int w = tid >> 6, l = tid & 63;
    const int q = blockIdx.x * 4 + w;

    *reinterpret_cast<float4*>(&qrow[w][l * 4]) =
        *reinterpret_cast<const float4*>(emb + (size_t)q * DIM + l * 4);

    unsigned v = 0xFFFFFFFFu;
    if (l < SLW) v = shortlist[(size_t)q * SLW + l];
    __syncthreads();

    // 64-lane bitonic sort ascending (packed u32; 8 pad lanes sort last)
#pragma unroll
    for (int k = 2; k <= 64; k <<= 1) {
#pragma unroll
        for (int j = k >> 1; j > 0; j >>= 1) {
            unsigned o = (unsigned)__shfl_xor((int)v, j, 64);
            bool keepmin = (((l & j) == 0) == ((l & k) == 0));
            unsigned mn = v < o ? v : o;
            unsigned mx = v < o ? o : v;
            v = keepmin ? mn : mx;
        }
    }

    const int cslot = l >> 3, part = l & 7;       // 8 cands x 8 lanes
    unsigned sel = (unsigned)__shfl((int)v, cslot, 64);
    int ci = (int)(sel & 0xFFFFu);

    float dv = 3.0e38f; int civ = 0x7fffffff;
    {
        const float* crow = emb + (size_t)ci * DIM + part * 32;   // 32 dims/lane
        const float* qr = &qrow[w][part * 32];
        float p0 = 0.f, p1 = 0.f, p2 = 0.f, p3 = 0.f;
#pragma unroll
        for (int kk = 0; kk < 8; ++kk) {
            float4 cv4 = *reinterpret_cast<const float4*>(crow + kk * 4);
            float4 qv4 = *reinterpret_cast<const float4*>(qr + kk * 4);
            p0 = fmaf(cv4.x, qv4.x, p0); p1 = fmaf(cv4.y, qv4.y, p1);
            p2 = fmaf(cv4.z, qv4.z, p2); p3 = fmaf(cv4.w, qv4.w, p3);
        }
        float p = (p0 + p1) + (p2 + p3);
        p += __shfl_xor(p, 1, 64);
        p += __shfl_xor(p, 2, 64);
        p += __shfl_xor(p, 4, 64);
        if (part == 0 && ci != q) { dv = fmaf(-2.0f, p, norms[q] + norms[ci]); civ = ci; }
    }

    // relocate the 8 (dist,idx) to every 8-lane coset: lane reads lane (l&7)*8
    float dv2 = __shfl(dv, (l & 7) * 8, 64);
    int  civ2 = __shfl(civ, (l & 7) * 8, 64);

    const int lq = labels[q];
    bool match = false;
#pragma unroll
    for (int r = 0; r < KNN; ++r) {
        float md = dv2; int mxi = civ2;
#pragma unroll
        for (int mask = 1; mask <= 4; mask <<= 1) {
            float pd = __shfl_xor(md, mask, 64);
            int   pi = __shfl_xor(mxi, mask, 64);
            if (pd < md || (pd == md && pi < mxi)) { md = pd; mxi = pi; }
        }
        if (civ2 == mxi) dv2 = 3.0e38f;   // owner copy retires in every coset
        match = match || (labels[mxi] == lq);
    }
    if (l == 0) atomicAdd(cnt, match ? 1 : 0);
}

// K3: scalar output = count / N (power-of-two divide, exact)
__global__ void finalize_kernel(const int* __restrict__ cnt, float* __restrict__ out) {
    if (threadIdx.x == 0) out[0] = (float)(*cnt) * (1.0f / (float)NPTS);
}

extern "C" void kernel_launch(void* const* d_in, const int* in_sizes, int n_in,
                              void* d_out, int out_size, void* d_ws, size_t ws_size,
                              hipStream_t stream) {
    (void)in_sizes; (void)n_in; (void)out_size; (void)ws_size;
    const float* emb    = (const float*)d_in[0];
    const int*   labels = (const int*)d_in[1];
    float*       out    = (float*)d_out;

    char* ws = (char*)d_ws;
    int*       cnt       = (int*)(ws + WS_CNT);
    float*     norms     = (float*)(ws + WS_NORMS);
    _Float16*  hiA       = (_Float16*)(ws + WS_HIA);
    unsigned*  shortlist = (unsigned*)(ws + WS_SL);

    prep_kernel<<<NPTS / 4, 256, 0, stream>>>(emb, norms, hiA, cnt);
    filter_kernel<<<(NPTS / RPB) * STRIPS, 512, 0, stream>>>(hiA, shortlist);
    rescore_kernel<<<NPTS / 4, 256, 0, stream>>>(emb, labels, norms, shortlist, cnt);
    finalize_kernel<<<1, 64, 0, stream>>>(cnt, out);
}

// Round 13
// 205.197 us; speedup vs baseline: 6.9661x; 1.8400x over previous
//
#include <hip/hip_runtime.h>

#define NPTS 16384
#define DIM 256
#define NKC 36                 // augmented kchunks: 32 data + [hc,lc] + [1,1,2] + 2 pad
#define KNN 5
#define RPB 256                // rows per block = 8 waves x 32
#define CTILE 64               // candidates per tile
#define STRIPS 8
#define STRIP (NPTS / STRIPS)  // 2048
#define NCB (STRIP / CTILE)    // 32
#define TOPS 7                 // per-strip shortlist depth (self + 5 + 1 spare)
#define SLW (STRIPS * TOPS)    // 56 shortlist slots per row
#define SEL 8                  // candidates rescored exactly per row
#define NRB (NPTS / 4)         // rescore blocks (4 rows each) = 4096

typedef _Float16 f16x8 __attribute__((ext_vector_type(8)));
typedef float    f32x4 __attribute__((ext_vector_type(4)));

// workspace byte offsets
#define WS_NORMS 4096                          // float [NPTS]
#define WS_HIA   (WS_NORMS + NPTS * 4)         // _Float16 [NKC][NPTS][8] k-major
#define WS_SL    (WS_HIA + NPTS * NKC * 16)    // unsigned [NPTS][SLW]
#define WS_PART  (WS_SL + NPTS * SLW * 4)      // int [NRB] per-block match counts

// pack positive fp16 score + 14-bit idx into one sortable u32
__device__ __forceinline__ unsigned packsi(float s, int idx) {
    union { _Float16 h; unsigned short u; } cv;
    cv.h = (_Float16)s;                       // RNE, score > 0 by construction
    return ((unsigned)cv.u << 16) | (unsigned)idx;
}

// compare-exchange (min/max) on packed u32 — 2 VALU ops, idx travels free
#define CEU(a, b) do {                                                        \
    unsigned mn_ = (a) < (b) ? (a) : (b);                                     \
    unsigned mx_ = (a) < (b) ? (b) : (a);                                     \
    (a) = mn_; (b) = mx_;                                                     \
} while (0)

// bubble x into ascending sorted TOPS-list of packed u32 (no-op if too big)
#define BUBBLE_U(Lp, x) do {                                                  \
    unsigned c_ = (x);                                                        \
    _Pragma("unroll")                                                         \
    for (int e_ = 0; e_ < TOPS; ++e_) {                                       \
        unsigned mn_ = c_ < Lp[e_] ? c_ : Lp[e_];                             \
        unsigned mx_ = c_ < Lp[e_] ? Lp[e_] : c_;                             \
        Lp[e_] = mn_; c_ = mx_;                                               \
    } } while (0)

// K0: k-major augmented fp16 buffer hiA[kc][row][8]:
// kc 0..31 = -2*fp16(row), kc32 = [h,l,0..] (h+l ~= ||row||^2),
// kc33 = [1,1,2,0..] (constant), kc34/35 = 0. Plus fp32 norms.
__global__ __launch_bounds__(256) void prep_kernel(const float* __restrict__ emb,
                                                   float* __restrict__ norms,
                                                   _Float16* __restrict__ hiA) {
    const int row = blockIdx.x * 4 + (threadIdx.x >> 6);
    const int l   = threadIdx.x & 63;
    float4 v = *reinterpret_cast<const float4*>(emb + (size_t)row * DIM + l * 4);
    union { _Float16 h[4]; short4 s; } u;
    u.h[0] = (_Float16)v.x * (_Float16)-2.0f;
    u.h[1] = (_Float16)v.y * (_Float16)-2.0f;
    u.h[2] = (_Float16)v.z * (_Float16)-2.0f;
    u.h[3] = (_Float16)v.w * (_Float16)-2.0f;
    *reinterpret_cast<short4*>(hiA + ((size_t)(l >> 1) * NPTS + row) * 8 + (l & 1) * 4) = u.s;

    float s = v.x * v.x + v.y * v.y + v.z * v.z + v.w * v.w;
#pragma unroll
    for (int off = 32; off > 0; off >>= 1) s += __shfl_down(s, off, 64);
    float tot = __shfl(s, 0, 64);
    if (l == 0) norms[row] = tot;
    if (l < 4) {   // chunks 32..35
        union { _Float16 h[4]; short4 s; } z0, z1;
        z0.h[0] = (_Float16)0.f; z0.h[1] = (_Float16)0.f;
        z0.h[2] = (_Float16)0.f; z0.h[3] = (_Float16)0.f;
        z1 = z0;
        if (l == 0) {
            _Float16 hh = (_Float16)tot;
            _Float16 ll = (_Float16)(tot - (float)hh);
            z0.h[0] = hh; z0.h[1] = ll;
        }
        if (l == 1) {   // A-side of the +||q||^2+4 fold
            z0.h[0] = (_Float16)1.0f; z0.h[1] = (_Float16)1.0f; z0.h[2] = (_Float16)2.0f;
        }
        _Float16* dst = hiA + ((size_t)(32 + l) * NPTS + row) * 8;
        *reinterpret_cast<short4*>(dst)     = z0.s;
        *reinterpret_cast<short4*>(dst + 4) = z1.s;
    }
}

// K1: MFMA filter — cf-major pipelined: MFMA burst of column cf overlaps the
// VALU epilogue of column cf-1 (per-acc t-order unchanged -> identical bits).
__global__ __launch_bounds__(512, 4) void filter_kernel(const _Float16* __restrict__ hiA,
                                                        unsigned* __restrict__ shortlist) {
    __shared__ _Float16 At[2 * NKC * CTILE * 8];   // 73728 B
    const int tid  = threadIdx.x;
    const int w    = tid >> 6;        // wave 0..7
    const int l    = tid & 63;
    const int lq16 = l & 15;          // D col = query-row-in-16
    const int lk4  = l >> 4;          // k-quarter / cand sub-group
    const int panel = blockIdx.x >> 3;
    const int strip = blockIdx.x & 7; // native XCD slot -> strip slice L2-resident
    const int qbase = panel * RPB;
    const int cand0 = strip * STRIP;
    const int rot   = panel & (NCB - 1);   // phase-decorrelated tile start

    // ---- B fragments resident: 2 rf x 8 t (kc = t*4+lk4), coalesced loads ----
    const size_t r0 = (size_t)qbase + w * 32 + lq16;
    f16x8 breg0[8], breg1[8];
#pragma unroll
    for (int t = 0; t < 8; ++t) {
        f16x8 v0 = *reinterpret_cast<const f16x8*>(hiA + ((size_t)(t * 4 + lk4) * NPTS + r0) * 8);
        f16x8 v1 = *reinterpret_cast<const f16x8*>(hiA + ((size_t)(t * 4 + lk4) * NPTS + r0 + 16) * 8);
#pragma unroll
        for (int e = 0; e < 8; ++e) {   // -0.5 * (-2q) = q, exact in fp16
            v0[e] = v0[e] * (_Float16)-0.5f;
            v1[e] = v1[e] * (_Float16)-0.5f;
        }
        breg0[t] = v0; breg1[t] = v1;
    }
    // augmented k-step (t=8): lk4=0 -> [1,1,0..] (picks hc+lc);
    // lk4=1 -> [hq,lq,2,0..] (picks hq+lq+4 against A's [1,1,2]); else 0.
    f16x8 b8_0 = 0, b8_1 = 0;
    {
        f16x8 raw0 = *reinterpret_cast<const f16x8*>(hiA + ((size_t)32 * NPTS + r0) * 8);
        f16x8 raw1 = *reinterpret_cast<const f16x8*>(hiA + ((size_t)32 * NPTS + r0 + 16) * 8);
        if (lk4 == 0) {
            b8_0[0] = (_Float16)1.0f; b8_0[1] = (_Float16)1.0f;
            b8_1[0] = (_Float16)1.0f; b8_1[1] = (_Float16)1.0f;
        } else if (lk4 == 1) {
            b8_0 = raw0; b8_0[2] = (_Float16)2.0f;
            b8_1 = raw1; b8_1[2] = (_Float16)2.0f;
        }
    }

    // ascending sorted top-7, packed u32
    unsigned Lp0[TOPS], Lp1[TOPS];
#pragma unroll
    for (int e = 0; e < TOPS; ++e) { Lp0[e] = 0xFFFFFFFFu; Lp1[e] = 0xFFFFFFFFu; }

    // waves 0..3 issue 9 loads per STAGE; waves 4..7 issue 8 (wave-uniform split)
#define STAGE(bufoff, tt) do {                                                \
    const int cbn_ = cand0 + (tt) * CTILE;                                    \
    _Pragma("unroll")                                                         \
    for (int i_ = 0; i_ < 4; ++i_) {                                          \
        int d_ = i_ * 8192 + tid * 16;                                        \
        int kc_ = d_ >> 10, cd_ = (d_ >> 4) & 63;                             \
        const _Float16* g_ = hiA + ((size_t)kc_ * NPTS + cbn_ + cd_) * 8;     \
        __builtin_amdgcn_global_load_lds(                                     \
            (const __attribute__((address_space(1))) void*)g_,                \
            (__attribute__((address_space(3))) void*)((char*)At + (bufoff) + d_), 16, 0, 0); \
    }                                                                         \
    if (tid < 256) {                                                          \
        int d_ = 32768 + tid * 16;                                            \
        int kc_ = d_ >> 10, cd_ = (d_ >> 4) & 63;                             \
        const _Float16* g_ = hiA + ((size_t)kc_ * NPTS + cbn_ + cd_) * 8;     \
        __builtin_amdgcn_global_load_lds(                                     \
            (const __attribute__((address_space(1))) void*)g_,                \
            (__attribute__((address_space(3))) void*)((char*)At + (bufoff) + d_), 16, 0, 0); \
    } } while (0)

// MFMA burst for candidate column cf: 9 k-steps x 2 rf (t ascending per acc)
#define MFMA_CF(cf) do {                                                      \
    _Pragma("unroll")                                                         \
    for (int t_ = 0; t_ < 9; ++t_) {                                          \
        f16x8 bf0_ = (t_ < 8) ? breg0[t_] : b8_0;                             \
        f16x8 bf1_ = (t_ < 8) ? breg1[t_] : b8_1;                             \
        f16x8 af_ = *reinterpret_cast<const f16x8*>(                          \
            Ab + (size_t)((t_ * 4 + lk4) * 64 + (cf) * 16 + lq16) * 16);      \
        acc0[cf] = __builtin_amdgcn_mfma_f32_16x16x32_f16(af_, bf0_, acc0[cf], 0, 0, 0); \
        acc1[cf] = __builtin_amdgcn_mfma_f32_16x16x32_f16(af_, bf1_, acc1[cf], 0, 0, 0); \
    } } while (0)

// epilogue for column cf: pack -> 4-CEU 2-smallest -> bubbles + guarded pair
#define EPI_CF(cf) do {                                                       \
    const int c0_ = cbase + (cf) * 16 + (lk4 << 2);                           \
    {                                                                         \
        unsigned p0 = packsi(acc0[cf][0], c0_ + 0);                           \
        unsigned p1 = packsi(acc0[cf][1], c0_ + 1);                           \
        unsigned p2 = packsi(acc0[cf][2], c0_ + 2);                           \
        unsigned p3 = packsi(acc0[cf][3], c0_ + 3);                           \
        CEU(p0, p1); CEU(p2, p3); CEU(p0, p2); CEU(p1, p2);                   \
        BUBBLE_U(Lp0, p0);                                                    \
        BUBBLE_U(Lp0, p1);                                                    \
        unsigned m23 = p2 < p3 ? p2 : p3;                                     \
        if (__any(m23 < Lp0[TOPS - 1])) { BUBBLE_U(Lp0, p2); BUBBLE_U(Lp0, p3); } \
    }                                                                         \
    {                                                                         \
        unsigned p0 = packsi(acc1[cf][0], c0_ + 0);                           \
        unsigned p1 = packsi(acc1[cf][1], c0_ + 1);                           \
        unsigned p2 = packsi(acc1[cf][2], c0_ + 2);                           \
        unsigned p3 = packsi(acc1[cf][3], c0_ + 3);                           \
        CEU(p0, p1); CEU(p2, p3); CEU(p0, p2); CEU(p1, p2);                   \
        BUBBLE_U(Lp1, p0);                                                    \
        BUBBLE_U(Lp1, p1);                                                    \
        unsigned m23 = p2 < p3 ? p2 : p3;                                     \
        if (__any(m23 < Lp1[TOPS - 1])) { BUBBLE_U(Lp1, p2); BUBBLE_U(Lp1, p3); } \
    } } while (0)

    STAGE(0, rot);

    int buf = 0;
    for (int cb = 0; cb < NCB; ++cb) {
        const int t_cur = (cb + rot) & (NCB - 1);
        // issue next-tile loads, then wait ONLY for the current tile's loads
        if (cb + 1 < NCB) {
            STAGE((buf ^ 1) * 36864, (cb + 1 + rot) & (NCB - 1));
            if (w < 4) { asm volatile("s_waitcnt vmcnt(9)" ::: "memory"); }
            else       { asm volatile("s_waitcnt vmcnt(8)" ::: "memory"); }
        } else {
            asm volatile("s_waitcnt vmcnt(0)" ::: "memory");
        }
        __builtin_amdgcn_sched_barrier(0);
        __builtin_amdgcn_s_barrier();      // all waves: current buf fully landed
        __builtin_amdgcn_sched_barrier(0);

        const char* Ab = (const char*)At + buf * 36864;
        const int cbase = cand0 + t_cur * CTILE;
        f32x4 acc0[4], acc1[4];
#pragma unroll
        for (int cf = 0; cf < 4; ++cf) {
            acc0[cf] = (f32x4){0.f, 0.f, 0.f, 0.f};
            acc1[cf] = (f32x4){0.f, 0.f, 0.f, 0.f};
        }

        // cf-major pipeline: MFMA burst cf overlaps epilogue of cf-1
        __builtin_amdgcn_s_setprio(1);
        MFMA_CF(0);
        MFMA_CF(1); EPI_CF(0);
        MFMA_CF(2); EPI_CF(1);
        MFMA_CF(3); EPI_CF(2);
        __builtin_amdgcn_s_setprio(0);
        EPI_CF(3);

        // fence buf reuse: LDS reads complete, then barrier (NO vmcnt drain)
        asm volatile("s_waitcnt lgkmcnt(0)" ::: "memory");
        __builtin_amdgcn_sched_barrier(0);
        __builtin_amdgcn_s_barrier();
        __builtin_amdgcn_sched_barrier(0);
        buf ^= 1;
    }
#undef STAGE
#undef MFMA_CF
#undef EPI_CF

    // ---- merge the 4 cand-partitions per row (snapshot butterfly over lk4) ----
#pragma unroll
    for (int mask = 16; mask <= 32; mask <<= 1) {
        unsigned pd[TOPS];
#pragma unroll
        for (int e = 0; e < TOPS; ++e)
            pd[e] = (unsigned)__shfl_xor((int)Lp0[e], mask, 64);
#pragma unroll
        for (int e = 0; e < TOPS; ++e) BUBBLE_U(Lp0, pd[e]);
#pragma unroll
        for (int e = 0; e < TOPS; ++e)
            pd[e] = (unsigned)__shfl_xor((int)Lp1[e], mask, 64);
#pragma unroll
        for (int e = 0; e < TOPS; ++e) BUBBLE_U(Lp1, pd[e]);
    }

    if (lk4 == 0) {   // lanes 0..15: final per-strip packed top-7 for both rows
        unsigned* dst0 = shortlist + r0 * SLW + strip * TOPS;
        unsigned* dst1 = shortlist + (r0 + 16) * SLW + strip * TOPS;
#pragma unroll
        for (int e = 0; e < TOPS; ++e) { dst0[e] = Lp0[e]; dst1[e] = Lp1[e]; }
    }
}

// K2: per row (one wave): bitonic-sort the 56 packed survivors across lanes,
// take the 8 lex-smallest, gather + exact fp32 rescore (8 lanes/cand),
// exact (dist, idx) lexicographic top-5, label match. NO global atomic:
// per-block match count goes to a private partials slot.
__global__ __launch_bounds__(256) void rescore_kernel(const float* __restrict__ emb,
                                                      const int* __restrict__ labels,
                                                      const float* __restrict__ norms,
                                                      const unsigned* __restrict__ shortlist,
                                                      int* __restrict__ partials) {
    __shared__ float qrow[4][DIM];
    __shared__ int   pc[4];
    const int tid = threadIdx.x;
    const int w = tid >> 6, l = tid & 63;
    const int q = blockIdx.x * 4 + w;

    *reinterpret_cast<float4*>(&qrow[w][l * 4]) =
        *reinterpret_cast<const float4*>(emb + (size_t)q * DIM + l * 4);

    unsigned v = 0xFFFFFFFFu;
    if (l < SLW) v = shortlist[(size_t)q * SLW + l];
    __syncthreads();

    // 64-lane bitonic sort ascending (packed u32; 8 pad lanes sort last)
#pragma unroll
    for (int k = 2; k <= 64; k <<= 1) {
#pragma unroll
        for (int j = k >> 1; j > 0; j >>= 1) {
            unsigned o = (unsigned)__shfl_xor((int)v, j, 64);
            bool keepmin = (((l & j) == 0) == ((l & k) == 0));
            unsigned mn = v < o ? v : o;
            unsigned mx = v < o ? o : v;
            v = keepmin ? mn : mx;
        }
    }

    const int cslot = l >> 3, part = l & 7;       // 8 cands x 8 lanes
    unsigned sel = (unsigned)__shfl((int)v, cslot, 64);
    int ci = (int)(sel & 0xFFFFu);

    float dv = 3.0e38f; int civ = 0x7fffffff;
    {
        const float* crow = emb + (size_t)ci * DIM + part * 32;   // 32 dims/lane
        const float* qr = &qrow[w][part * 32];
        float p0 = 0.f, p1 = 0.f, p2 = 0.f, p3 = 0.f;
#pragma unroll
        for (int kk = 0; kk < 8; ++kk) {
            float4 cv4 = *reinterpret_cast<const float4*>(crow + kk * 4);
            float4 qv4 = *reinterpret_cast<const float4*>(qr + kk * 4);
            p0 = fmaf(cv4.x, qv4.x, p0); p1 = fmaf(cv4.y, qv4.y, p1);
            p2 = fmaf(cv4.z, qv4.z, p2); p3 = fmaf(cv4.w, qv4.w, p3);
        }
        float p = (p0 + p1) + (p2 + p3);
        p += __shfl_xor(p, 1, 64);
        p += __shfl_xor(p, 2, 64);
        p += __shfl_xor(p, 4, 64);
        if (part == 0 && ci != q) { dv = fmaf(-2.0f, p, norms[q] + norms[ci]); civ = ci; }
    }

    // relocate the 8 (dist,idx) to every 8-lane coset: lane reads lane (l&7)*8
    float dv2 = __shfl(dv, (l & 7) * 8, 64);
    int  civ2 = __shfl(civ, (l & 7) * 8, 64);

    const int lq = labels[q];
    bool match = false;
#pragma unroll
    for (int r = 0; r < KNN; ++r) {
        float md = dv2; int mxi = civ2;
#pragma unroll
        for (int mask = 1; mask <= 4; mask <<= 1) {
            float pd = __shfl_xor(md, mask, 64);
            int   pi = __shfl_xor(mxi, mask, 64);
            if (pd < md || (pd == md && pi < mxi)) { md = pd; mxi = pi; }
        }
        if (civ2 == mxi) dv2 = 3.0e38f;   // owner copy retires in every coset
        match = match || (labels[mxi] == lq);
    }
    if (l == 0) pc[w] = match ? 1 : 0;
    __syncthreads();
    if (tid == 0) partials[blockIdx.x] = pc[0] + pc[1] + pc[2] + pc[3];
}

// K3: tree-reduce the 4096 per-block partials; out = sum / N (exact pow2 div)
__global__ __launch_bounds__(1024) void finalize_kernel(const int* __restrict__ partials,
                                                        float* __restrict__ out) {
    __shared__ int ws[16];
    const int tid = threadIdx.x;
    int4 v = *reinterpret_cast<const int4*>(partials + tid * 4);
    int s = v.x + v.y + v.z + v.w;
#pragma unroll
    for (int off = 32; off > 0; off >>= 1) s += __shfl_down(s, off, 64);
    if ((tid & 63) == 0) ws[tid >> 6] = s;
    __syncthreads();
    if (tid < 16) {
        int t = ws[tid];
#pragma unroll
        for (int off = 8; off > 0; off >>= 1) t += __shfl_down(t, off, 64);
        if (tid == 0) out[0] = (float)t * (1.0f / (float)NPTS);
    }
}

extern "C" void kernel_launch(void* const* d_in, const int* in_sizes, int n_in,
                              void* d_out, int out_size, void* d_ws, size_t ws_size,
                              hipStream_t stream) {
    (void)in_sizes; (void)n_in; (void)out_size; (void)ws_size;
    const float* emb    = (const float*)d_in[0];
    const int*   labels = (const int*)d_in[1];
    float*       out    = (float*)d_out;

    char* ws = (char*)d_ws;
    float*     norms     = (float*)(ws + WS_NORMS);
    _Float16*  hiA       = (_Float16*)(ws + WS_HIA);
    unsigned*  shortlist = (unsigned*)(ws + WS_SL);
    int*       partials  = (int*)(ws + WS_PART);

    prep_kernel<<<NPTS / 4, 256, 0, stream>>>(emb, norms, hiA);
    filter_kernel<<<(NPTS / RPB) * STRIPS, 512, 0, stream>>>(hiA, shortlist);
    rescore_kernel<<<NRB, 256, 0, stream>>>(emb, labels, norms, shortlist, partials);
    finalize_kernel<<<1, 1024, 0, stream>>>(partials, out);
}

// Round 14
// 195.776 us; speedup vs baseline: 7.3013x; 1.0481x over previous
//
#include <hip/hip_runtime.h>

#define NPTS 16384
#define DIM 256
#define NKC 36                 // augmented kchunks: 32 data + [hc,lc] + [1,1,2] + 2 pad
#define KNN 5
#define RPB 256                // rows per block = 8 waves x 32
#define CTILE 64               // candidates per tile
#define STRIPS 8
#define STRIP (NPTS / STRIPS)  // 2048
#define NCB (STRIP / CTILE)    // 32
#define TOPS 7                 // per-strip shortlist depth (self + 5 + 1 spare)
#define SLW (STRIPS * TOPS)    // 56 shortlist slots per row
#define SEL 8                  // candidates rescored exactly per row
#define NRB (NPTS / 4)         // rescore blocks (4 rows each) = 4096

typedef _Float16 f16x8 __attribute__((ext_vector_type(8)));
typedef float    f32x4 __attribute__((ext_vector_type(4)));

// workspace byte offsets
#define WS_NORMS 4096                          // float [NPTS]
#define WS_HIA   (WS_NORMS + NPTS * 4)         // _Float16 [NKC][NPTS][8] k-major
#define WS_SL    (WS_HIA + NPTS * NKC * 16)    // unsigned [NPTS][SLW]
#define WS_PART  (WS_SL + NPTS * SLW * 4)      // int [NRB] per-block match counts

// pack positive fp16 score + 14-bit idx into one sortable u32
__device__ __forceinline__ unsigned packsi(float s, int idx) {
    union { _Float16 h; unsigned short u; } cv;
    cv.h = (_Float16)s;                       // RNE, score > 0 by construction
    return ((unsigned)cv.u << 16) | (unsigned)idx;
}

__device__ __forceinline__ unsigned umed3(unsigned a, unsigned b, unsigned c) {
    unsigned d;
    asm("v_med3_u32 %0, %1, %2, %3" : "=v"(d) : "v"(a), "v"(b), "v"(c));
    return d;
}

// compare-exchange (min/max) on packed u32 — 2 VALU ops, idx travels free
#define CEU(a, b) do {                                                        \
    unsigned mn_ = (a) < (b) ? (a) : (b);                                     \
    unsigned mx_ = (a) < (b) ? (b) : (a);                                     \
    (a) = mn_; (b) = mx_;                                                     \
} while (0)

// med3 sorted-insert into ascending TOPS-list (identical result to min/max
// bubble, 7 ops instead of 14): L'[0]=min(L0,x); L'[e]=med3(x, L[e], oldL[e-1])
#define BUBBLE_U(Lp, x) do {                                                  \
    unsigned c_ = (x);                                                        \
    unsigned po_ = Lp[0];                                                     \
    Lp[0] = c_ < po_ ? c_ : po_;                                              \
    _Pragma("unroll")                                                         \
    for (int e_ = 1; e_ < TOPS; ++e_) {                                       \
        unsigned cur_ = Lp[e_];                                               \
        Lp[e_] = umed3(c_, cur_, po_);                                        \
        po_ = cur_;                                                           \
    } } while (0)

// K0: k-major augmented fp16 buffer hiA[kc][row][8]:
// kc 0..31 = -2*fp16(row), kc32 = [h,l,0..] (h+l ~= ||row||^2),
// kc33 = [1,1,2,0..] (constant), kc34/35 = 0. Plus fp32 norms.
__global__ __launch_bounds__(256) void prep_kernel(const float* __restrict__ emb,
                                                   float* __restrict__ norms,
                                                   _Float16* __restrict__ hiA) {
    const int row = blockIdx.x * 4 + (threadIdx.x >> 6);
    const int l   = threadIdx.x & 63;
    float4 v = *reinterpret_cast<const float4*>(emb + (size_t)row * DIM + l * 4);
    union { _Float16 h[4]; short4 s; } u;
    u.h[0] = (_Float16)v.x * (_Float16)-2.0f;
    u.h[1] = (_Float16)v.y * (_Float16)-2.0f;
    u.h[2] = (_Float16)v.z * (_Float16)-2.0f;
    u.h[3] = (_Float16)v.w * (_Float16)-2.0f;
    *reinterpret_cast<short4*>(hiA + ((size_t)(l >> 1) * NPTS + row) * 8 + (l & 1) * 4) = u.s;

    float s = v.x * v.x + v.y * v.y + v.z * v.z + v.w * v.w;
#pragma unroll
    for (int off = 32; off > 0; off >>= 1) s += __shfl_down(s, off, 64);
    float tot = __shfl(s, 0, 64);
    if (l == 0) norms[row] = tot;
    if (l < 4) {   // chunks 32..35
        union { _Float16 h[4]; short4 s; } z0, z1;
        z0.h[0] = (_Float16)0.f; z0.h[1] = (_Float16)0.f;
        z0.h[2] = (_Float16)0.f; z0.h[3] = (_Float16)0.f;
        z1 = z0;
        if (l == 0) {
            _Float16 hh = (_Float16)tot;
            _Float16 ll = (_Float16)(tot - (float)hh);
            z0.h[0] = hh; z0.h[1] = ll;
        }
        if (l == 1) {   // A-side of the +||q||^2+4 fold
            z0.h[0] = (_Float16)1.0f; z0.h[1] = (_Float16)1.0f; z0.h[2] = (_Float16)2.0f;
        }
        _Float16* dst = hiA + ((size_t)(32 + l) * NPTS + row) * 8;
        *reinterpret_cast<short4*>(dst)     = z0.s;
        *reinterpret_cast<short4*>(dst + 4) = z1.s;
    }
}

// K1: MFMA filter — cf-major pipelined; EPI of column 3 deferred into the next
// tile's MFMA burst (acc hoisted above the loop; peeled EPI3 after the loop).
__global__ __launch_bounds__(512, 4) void filter_kernel(const _Float16* __restrict__ hiA,
                                                        unsigned* __restrict__ shortlist) {
    __shared__ _Float16 At[2 * NKC * CTILE * 8];   // 73728 B
    const int tid  = threadIdx.x;
    const int w    = tid >> 6;        // wave 0..7
    const int l    = tid & 63;
    const int lq16 = l & 15;          // D col = query-row-in-16
    const int lk4  = l >> 4;          // k-quarter / cand sub-group
    const int panel = blockIdx.x >> 3;
    const int strip = blockIdx.x & 7; // native XCD slot -> strip slice L2-resident
    const int qbase = panel * RPB;
    const int cand0 = strip * STRIP;
    const int rot   = panel & (NCB - 1);   // phase-decorrelated tile start

    // ---- B fragments resident: 2 rf x 8 t (kc = t*4+lk4), coalesced loads ----
    const size_t r0 = (size_t)qbase + w * 32 + lq16;
    f16x8 breg0[8], breg1[8];
#pragma unroll
    for (int t = 0; t < 8; ++t) {
        f16x8 v0 = *reinterpret_cast<const f16x8*>(hiA + ((size_t)(t * 4 + lk4) * NPTS + r0) * 8);
        f16x8 v1 = *reinterpret_cast<const f16x8*>(hiA + ((size_t)(t * 4 + lk4) * NPTS + r0 + 16) * 8);
#pragma unroll
        for (int e = 0; e < 8; ++e) {   // -0.5 * (-2q) = q, exact in fp16
            v0[e] = v0[e] * (_Float16)-0.5f;
            v1[e] = v1[e] * (_Float16)-0.5f;
        }
        breg0[t] = v0; breg1[t] = v1;
    }
    // augmented k-step (t=8): lk4=0 -> [1,1,0..] (picks hc+lc);
    // lk4=1 -> [hq,lq,2,0..] (picks hq+lq+4 against A's [1,1,2]); else 0.
    f16x8 b8_0 = 0, b8_1 = 0;
    {
        f16x8 raw0 = *reinterpret_cast<const f16x8*>(hiA + ((size_t)32 * NPTS + r0) * 8);
        f16x8 raw1 = *reinterpret_cast<const f16x8*>(hiA + ((size_t)32 * NPTS + r0 + 16) * 8);
        if (lk4 == 0) {
            b8_0[0] = (_Float16)1.0f; b8_0[1] = (_Float16)1.0f;
            b8_1[0] = (_Float16)1.0f; b8_1[1] = (_Float16)1.0f;
        } else if (lk4 == 1) {
            b8_0 = raw0; b8_0[2] = (_Float16)2.0f;
            b8_1 = raw1; b8_1[2] = (_Float16)2.0f;
        }
    }

    // ascending sorted top-7, packed u32
    unsigned Lp0[TOPS], Lp1[TOPS];
#pragma unroll
    for (int e = 0; e < TOPS; ++e) { Lp0[e] = 0xFFFFFFFFu; Lp1[e] = 0xFFFFFFFFu; }

    // waves 0..3 issue 9 loads per STAGE; waves 4..7 issue 8 (wave-uniform split)
#define STAGE(bufoff, tt) do {                                                \
    const int cbn_ = cand0 + (tt) * CTILE;                                    \
    _Pragma("unroll")                                                         \
    for (int i_ = 0; i_ < 4; ++i_) {                                          \
        int d_ = i_ * 8192 + tid * 16;                                        \
        int kc_ = d_ >> 10, cd_ = (d_ >> 4) & 63;                             \
        const _Float16* g_ = hiA + ((size_t)kc_ * NPTS + cbn_ + cd_) * 8;     \
        __builtin_amdgcn_global_load_lds(                                     \
            (const __attribute__((address_space(1))) void*)g_,                \
            (__attribute__((address_space(3))) void*)((char*)At + (bufoff) + d_), 16, 0, 0); \
    }                                                                         \
    if (tid < 256) {                                                          \
        int d_ = 32768 + tid * 16;                                            \
        int kc_ = d_ >> 10, cd_ = (d_ >> 4) & 63;                             \
        const _Float16* g_ = hiA + ((size_t)kc_ * NPTS + cbn_ + cd_) * 8;     \
        __builtin_amdgcn_global_load_lds(                                     \
            (const __attribute__((address_space(1))) void*)g_,                \
            (__attribute__((address_space(3))) void*)((char*)At + (bufoff) + d_), 16, 0, 0); \
    } } while (0)

// MFMA burst for candidate column cf: 9 k-steps x 2 rf (t ascending per acc)
#define MFMA_CF(cf) do {                                                      \
    _Pragma("unroll")                                                         \
    for (int t_ = 0; t_ < 9; ++t_) {                                          \
        f16x8 bf0_ = (t_ < 8) ? breg0[t_] : b8_0;                             \
        f16x8 bf1_ = (t_ < 8) ? breg1[t_] : b8_1;                             \
        f16x8 af_ = *reinterpret_cast<const f16x8*>(                          \
            Ab + (size_t)((t_ * 4 + lk4) * 64 + (cf) * 16 + lq16) * 16);      \
        acc0[cf] = __builtin_amdgcn_mfma_f32_16x16x32_f16(af_, bf0_, acc0[cf], 0, 0, 0); \
        acc1[cf] = __builtin_amdgcn_mfma_f32_16x16x32_f16(af_, bf1_, acc1[cf], 0, 0, 0); \
    } } while (0)

// epilogue for column cf against base cbx: pack -> 4-CEU -> med3 bubbles
#define EPI_CF(cf, cbx) do {                                                  \
    const int c0_ = (cbx) + (cf) * 16 + (lk4 << 2);                           \
    {                                                                         \
        unsigned p0 = packsi(acc0[cf][0], c0_ + 0);                           \
        unsigned p1 = packsi(acc0[cf][1], c0_ + 1);                           \
        unsigned p2 = packsi(acc0[cf][2], c0_ + 2);                           \
        unsigned p3 = packsi(acc0[cf][3], c0_ + 3);                           \
        CEU(p0, p1); CEU(p2, p3); CEU(p0, p2); CEU(p1, p2);                   \
        BUBBLE_U(Lp0, p0);                                                    \
        BUBBLE_U(Lp0, p1);                                                    \
        unsigned m23 = p2 < p3 ? p2 : p3;                                     \
        if (__any(m23 < Lp0[TOPS - 1])) { BUBBLE_U(Lp0, p2); BUBBLE_U(Lp0, p3); } \
    }                                                                         \
    {                                                                         \
        unsigned p0 = packsi(acc1[cf][0], c0_ + 0);                           \
        unsigned p1 = packsi(acc1[cf][1], c0_ + 1);                           \
        unsigned p2 = packsi(acc1[cf][2], c0_ + 2);                           \
        unsigned p3 = packsi(acc1[cf][3], c0_ + 3);                           \
        CEU(p0, p1); CEU(p2, p3); CEU(p0, p2); CEU(p1, p2);                   \
        BUBBLE_U(Lp1, p0);                                                    \
        BUBBLE_U(Lp1, p1);                                                    \
        unsigned m23 = p2 < p3 ? p2 : p3;                                     \
        if (__any(m23 < Lp1[TOPS - 1])) { BUBBLE_U(Lp1, p2); BUBBLE_U(Lp1, p3); } \
    } } while (0)

    STAGE(0, rot);

    int buf = 0;
    int cbase_prev = 0;
    f32x4 acc0[4], acc1[4];    // hoisted: acc[3] must survive across the barrier
    for (int cb = 0; cb < NCB; ++cb) {
        const int t_cur = (cb + rot) & (NCB - 1);
        // issue next-tile loads, then wait ONLY for the current tile's loads
        if (cb + 1 < NCB) {
            STAGE((buf ^ 1) * 36864, (cb + 1 + rot) & (NCB - 1));
            if (w < 4) { asm volatile("s_waitcnt vmcnt(9)" ::: "memory"); }
            else       { asm volatile("s_waitcnt vmcnt(8)" ::: "memory"); }
        } else {
            asm volatile("s_waitcnt vmcnt(0)" ::: "memory");
        }
        __builtin_amdgcn_sched_barrier(0);
        __builtin_amdgcn_s_barrier();      // all waves: current buf fully landed
        __builtin_amdgcn_sched_barrier(0);

        const char* Ab = (const char*)At + buf * 36864;
        const int cbase = cand0 + t_cur * CTILE;
#pragma unroll
        for (int cf = 0; cf < 3; ++cf) {   // acc[3] init deferred until EPI3(prev) ran
            acc0[cf] = (f32x4){0.f, 0.f, 0.f, 0.f};
            acc1[cf] = (f32x4){0.f, 0.f, 0.f, 0.f};
        }

        // cf-major pipeline; deferred EPI3(prev) overlaps this tile's MFMA
        __builtin_amdgcn_s_setprio(1);
        MFMA_CF(0);
        if (cb > 0) { EPI_CF(3, cbase_prev); }
        acc0[3] = (f32x4){0.f, 0.f, 0.f, 0.f};
        acc1[3] = (f32x4){0.f, 0.f, 0.f, 0.f};
        MFMA_CF(1); EPI_CF(0, cbase);
        MFMA_CF(2); EPI_CF(1, cbase);
        MFMA_CF(3); EPI_CF(2, cbase);
        __builtin_amdgcn_s_setprio(0);

        // fence buf reuse: LDS reads complete, then barrier (NO vmcnt drain)
        asm volatile("s_waitcnt lgkmcnt(0)" ::: "memory");
        __builtin_amdgcn_sched_barrier(0);
        __builtin_amdgcn_s_barrier();
        __builtin_amdgcn_sched_barrier(0);
        cbase_prev = cbase;
        buf ^= 1;
    }
    EPI_CF(3, cbase_prev);   // peeled: last tile's column-3 epilogue
#undef STAGE
#undef MFMA_CF
#undef EPI_CF

    // ---- merge the 4 cand-partitions per row (snapshot butterfly over lk4) ----
#pragma unroll
    for (int mask = 16; mask <= 32; mask <<= 1) {
        unsigned pd[TOPS];
#pragma unroll
        for (int e = 0; e < TOPS; ++e)
            pd[e] = (unsigned)__shfl_xor((int)Lp0[e], mask, 64);
#pragma unroll
        for (int e = 0; e < TOPS; ++e) BUBBLE_U(Lp0, pd[e]);
#pragma unroll
        for (int e = 0; e < TOPS; ++e)
            pd[e] = (unsigned)__shfl_xor((int)Lp1[e], mask, 64);
#pragma unroll
        for (int e = 0; e < TOPS; ++e) BUBBLE_U(Lp1, pd[e]);
    }

    if (lk4 == 0) {   // lanes 0..15: final per-strip packed top-7 for both rows
        unsigned* dst0 = shortlist + r0 * SLW + strip * TOPS;
        unsigned* dst1 = shortlist + (r0 + 16) * SLW + strip * TOPS;
#pragma unroll
        for (int e = 0; e < TOPS; ++e) { dst0[e] = Lp0[e]; dst1[e] = Lp1[e]; }
    }
}

// K2: per row (one wave): bitonic-sort the 56 packed survivors across lanes,
// take the 8 lex-smallest, gather + exact fp32 rescore (8 lanes/cand),
// exact (dist, idx) lexicographic top-5, label match; partials slot (no atomic).
__global__ __launch_bounds__(256) void rescore_kernel(const float* __restrict__ emb,
                                                      const int* __restrict__ labels,
                                                      const float* __restrict__ norms,
                                                      const unsigned* __restrict__ shortlist,
                                                      int* __restrict__ partials) {
    __shared__ float qrow[4][DIM];
    __shared__ int   pc[4];
    const int tid = threadIdx.x;
    const int w = tid >> 6, l = tid & 63;
    const int q = blockIdx.x * 4 + w;

    *reinterpret_cast<float4*>(&qrow[w][l * 4]) =
        *reinterpret_cast<const float4*>(emb + (size_t)q * DIM + l * 4);

    unsigned v = 0xFFFFFFFFu;
    if (l < SLW) v = shortlist[(size_t)q * SLW + l];
    __syncthreads();

    // 64-lane bitonic sort ascending (packed u32; 8 pad lanes sort last)
#pragma unroll
    for (int k = 2; k <= 64; k <<= 1) {
#pragma unroll
        for (int j = k >> 1; j > 0; j >>= 1) {
            unsigned o = (unsigned)__shfl_xor((int)v, j, 64);
            bool keepmin = (((l & j) == 0) == ((l & k) == 0));
            unsigned mn = v < o ? v : o;
            unsigned mx = v < o ? o : v;
            v = keepmin ? mn : mx;
        }
    }

    const int cslot = l >> 3, part = l & 7;       // 8 cands x 8 lanes
    unsigned sel = (unsigned)__shfl((int)v, cslot, 64);
    int ci = (int)(sel & 0xFFFFu);

    float dv = 3.0e38f; int civ = 0x7fffffff;
    {
        const float* crow = emb + (size_t)ci * DIM + part * 32;   // 32 dims/lane
        const float* qr = &qrow[w][part * 32];
        float p0 = 0.f, p1 = 0.f, p2 = 0.f, p3 = 0.f;
#pragma unroll
        for (int kk = 0; kk < 8; ++kk) {
            float4 cv4 = *reinterpret_cast<const float4*>(crow + kk * 4);
            float4 qv4 = *reinterpret_cast<const float4*>(qr + kk * 4);
            p0 = fmaf(cv4.x, qv4.x, p0); p1 = fmaf(cv4.y, qv4.y, p1);
            p2 = fmaf(cv4.z, qv4.z, p2); p3 = fmaf(cv4.w, qv4.w, p3);
        }
        float p = (p0 + p1) + (p2 + p3);
        p += __shfl_xor(p, 1, 64);
        p += __shfl_xor(p, 2, 64);
        p += __shfl_xor(p, 4, 64);
        if (part == 0 && ci != q) { dv = fmaf(-2.0f, p, norms[q] + norms[ci]); civ = ci; }
    }

    // relocate the 8 (dist,idx) to every 8-lane coset: lane reads lane (l&7)*8
    float dv2 = __shfl(dv, (l & 7) * 8, 64);
    int  civ2 = __shfl(civ, (l & 7) * 8, 64);

    const int lq = labels[q];
    bool match = false;
#pragma unroll
    for (int r = 0; r < KNN; ++r) {
        float md = dv2; int mxi = civ2;
#pragma unroll
        for (int mask = 1; mask <= 4; mask <<= 1) {
            float pd = __shfl_xor(md, mask, 64);
            int   pi = __shfl_xor(mxi, mask, 64);
            if (pd < md || (pd == md && pi < mxi)) { md = pd; mxi = pi; }
        }
        if (civ2 == mxi) dv2 = 3.0e38f;   // owner copy retires in every coset
        match = match || (labels[mxi] == lq);
    }
    if (l == 0) pc[w] = match ? 1 : 0;
    __syncthreads();
    if (tid == 0) partials[blockIdx.x] = pc[0] + pc[1] + pc[2] + pc[3];
}

// K3: tree-reduce the 4096 per-block partials; out = sum / N (exact pow2 div)
__global__ __launch_bounds__(1024) void finalize_kernel(const int* __restrict__ partials,
                                                        float* __restrict__ out) {
    __shared__ int ws[16];
    const int tid = threadIdx.x;
    int4 v = *reinterpret_cast<const int4*>(partials + tid * 4);
    int s = v.x + v.y + v.z + v.w;
#pragma unroll
    for (int off = 32; off > 0; off >>= 1) s += __shfl_down(s, off, 64);
    if ((tid & 63) == 0) ws[tid >> 6] = s;
    __syncthreads();
    if (tid < 16) {
        int t = ws[tid];
#pragma unroll
        for (int off = 8; off > 0; off >>= 1) t += __shfl_down(t, off, 64);
        if (tid == 0) out[0] = (float)t * (1.0f / (float)NPTS);
    }
}

extern "C" void kernel_launch(void* const* d_in, const int* in_sizes, int n_in,
                              void* d_out, int out_size, void* d_ws, size_t ws_size,
                              hipStream_t stream) {
    (void)in_sizes; (void)n_in; (void)out_size; (void)ws_size;
    const float* emb    = (const float*)d_in[0];
    const int*   labels = (const int*)d_in[1];
    float*       out    = (float*)d_out;

    char* ws = (char*)d_ws;
    float*     norms     = (float*)(ws + WS_NORMS);
    _Float16*  hiA       = (_Float16*)(ws + WS_HIA);
    unsigned*  shortlist = (unsigned*)(ws + WS_SL);
    int*       partials  = (int*)(ws + WS_PART);

    prep_kernel<<<NPTS / 4, 256, 0, stream>>>(emb, norms, hiA);
    filter_kernel<<<(NPTS / RPB) * STRIPS, 512, 0, stream>>>(hiA, shortlist);
    rescore_kernel<<<NRB, 256, 0, stream>>>(emb, labels, norms, shortlist, partials);
    finalize_kernel<<<1, 1024, 0, stream>>>(partials, out);
}